// Round 7
// baseline (181.838 us; speedup 1.0000x reference)
//
#include <hip/hip_runtime.h>

typedef __attribute__((ext_vector_type(8))) short bf16x8;
typedef __attribute__((ext_vector_type(4))) float f32x4;
typedef __attribute__((ext_vector_type(4))) unsigned short u16x4;

#define MFMA16(a, b, c) __builtin_amdgcn_mfma_f32_16x16x32_bf16((a), (b), (c), 0, 0, 0)

static constexpr int D_MODEL = 1024;
static constexpr int SEQ = 2048;
static constexpr int NH = 16;
static constexpr int HD = 64;
static constexpr int LDA = 40;   // slow-path GEMM LDS row stride
static constexpr int MST = 136;  // V^T repack LDS row stride (elems)
static constexpr float NEG_BIG = -1.0e30f;

__device__ __forceinline__ unsigned short f2bf(float f) {
  union { float f; unsigned int u; } v; v.f = f;
  unsigned int r = v.u + 0x7fffu + ((v.u >> 16) & 1u);
  return (unsigned short)(r >> 16);
}

// packed f32x2 -> bf16x2 (RNE), one VALU op
__device__ __forceinline__ unsigned int cvtpk_bf16(float a, float b) {
  unsigned int r;
  asm("v_cvt_pk_bf16_f32 %0, %1, %2" : "=v"(r) : "v"(a), "v"(b));
  return r;
}

// Adaptive 8-element load: bf16 direct, or f32 -> RNE bf16 convert (slow path).
__device__ __forceinline__ bf16x8 ld8(const void* p, size_t eidx, int bf) {
  if (bf) return *(const bf16x8*)((const unsigned short*)p + eidx);
  const float* f = (const float*)p + eidx;
  f32x4 lo = *(const f32x4*)f;
  f32x4 hi = *(const f32x4*)(f + 4);
  bf16x8 r;
  r[0] = (short)f2bf(lo[0]); r[1] = (short)f2bf(lo[1]);
  r[2] = (short)f2bf(lo[2]); r[3] = (short)f2bf(lo[3]);
  r[4] = (short)f2bf(hi[0]); r[5] = (short)f2bf(hi[1]);
  r[6] = (short)f2bf(hi[2]); r[7] = (short)f2bf(hi[3]);
  return r;
}

// async global -> LDS, 16B per lane (dst = wave-uniform base + lane*16)
__device__ __forceinline__ void async16(const unsigned short* g, unsigned short* l) {
  __builtin_amdgcn_global_load_lds(
      (const __attribute__((address_space(1))) void*)g,
      (__attribute__((address_space(3))) void*)l, 16, 0, 0);
}

// ---- dtype detector ----
__global__ __launch_bounds__(64) void detect_kernel(
    const unsigned short* __restrict__ xs, int* __restrict__ flag) {
  int lane = threadIdx.x;
  unsigned short s = xs[2 * lane];
  int e = (s >> 7) & 0xFF;
  bool hit = (e >= 117 && e <= 129);
  unsigned long long m = __ballot(hit);
  if (lane == 0) { flag[0] = (__popcll(m) >= 32) ? 1 : 0; flag[1] = 1; }
}

// ---- pre-convert X and the four W matrices to bf16 (fast path) ----
__global__ __launch_bounds__(256) void convert_kernel(
    const void* __restrict__ X,
    const void* __restrict__ W0, const void* __restrict__ W1,
    const void* __restrict__ W2, const void* __restrict__ W3,
    const int* __restrict__ flag,
    unsigned short* __restrict__ Xb, unsigned short* __restrict__ Wb)
{
  const int bf = *flag;
  const int ty = blockIdx.y;
  const void* src; unsigned short* dst; size_t n;
  if (ty == 0) { src = X; dst = Xb; n = (size_t)2 * SEQ * D_MODEL; }
  else {
    src = (ty == 1) ? W0 : (ty == 2) ? W1 : (ty == 3) ? W2 : W3;
    dst = Wb + (size_t)(ty - 1) * D_MODEL * D_MODEL;
    n = (size_t)D_MODEL * D_MODEL;
  }
  size_t i = ((size_t)blockIdx.x * 256 + threadIdx.x) * 8;
  if (i >= n) return;
  *(bf16x8*)(dst + i) = ld8(src, i, bf);
}

// ======================= FAST PATH bf16 GEMM =======================
// 128x128 tile, BK=32, TRIPLE-BUFFERED depth-2 prefetch (attn-validated
// schedule): stage item f+2 each iter; counted vmcnt(4) wait + raw s_barrier
// -> each stage gets ~2 compute phases to land. 48 KB LDS -> 3 blocks/CU.
// Swizzle (32-elem rows): LDS[r][c] = G[r][c ^ ((r>>1)&3)].
__device__ __forceinline__ void gemm_fast_core(
    const unsigned short* __restrict__ A, const unsigned short* __restrict__ B,
    int tm, int tn, unsigned short* smem, f32x4 acc[4][4])
{
  const int t = threadIdx.x;
  const int lane = t & 63;
  const int w = t >> 6;
  const int wm = (w >> 1) * 64, wn = (w & 1) * 64;
  const int quad = lane >> 4, l16 = lane & 15;
  const int srow = lane >> 2;                          // 16 rows per async16
  const int scol = ((lane & 3) ^ ((lane >> 3) & 3)) * 8;  // swizzled src chunk
  const int xa = (l16 >> 1) & 3;                       // read-side swizzle key

#pragma unroll
  for (int mi = 0; mi < 4; ++mi)
#pragma unroll
    for (int ni = 0; ni < 4; ++ni)
      acc[mi][ni] = (f32x4){0.f, 0.f, 0.f, 0.f};

  // stage K-tile f (32 wide) into buffer buf: 4 async16 per thread
  auto stage = [&](int f, int buf) {
    const int k0 = f * 32;
    unsigned short* dst = smem + buf * 8192;
#pragma unroll
    for (int i = 0; i < 2; ++i) {
      const int row = w * 32 + i * 16;
      async16(A + (size_t)(tm + row + srow) * D_MODEL + k0 + scol,
              dst + row * 32);
      async16(B + (size_t)(tn + row + srow) * D_MODEL + k0 + scol,
              dst + 4096 + row * 32);
    }
  };

  stage(0, 0);
  stage(1, 1);

  int cur = 0, nb = 2;
  for (int f = 0; f < 32; ++f) {
    if (f + 1 < 32) asm volatile("s_waitcnt vmcnt(4)" ::: "memory");
    else            asm volatile("s_waitcnt vmcnt(0)" ::: "memory");
    __builtin_amdgcn_s_barrier();            // raw: no forced vmcnt(0) drain
    __builtin_amdgcn_sched_barrier(0);       // pin LDS reads behind barrier
    if (f + 2 < 32) stage(f + 2, nb);
    const unsigned short* As = smem + cur * 8192;
    const unsigned short* Bs = As + 4096;
    bf16x8 af[4], bfv[4];
#pragma unroll
    for (int mi = 0; mi < 4; ++mi)
      af[mi] = *(const bf16x8*)(As + (wm + mi * 16 + l16) * 32 + (quad ^ xa) * 8);
#pragma unroll
    for (int ni = 0; ni < 4; ++ni)
      bfv[ni] = *(const bf16x8*)(Bs + (wn + ni * 16 + l16) * 32 + (quad ^ xa) * 8);
    __builtin_amdgcn_s_setprio(1);
#pragma unroll
    for (int mi = 0; mi < 4; ++mi)
#pragma unroll
      for (int ni = 0; ni < 4; ++ni)
        acc[mi][ni] = MFMA16(af[mi], bfv[ni], acc[mi][ni]);
    __builtin_amdgcn_s_setprio(0);
    cur = (cur == 2) ? 0 : cur + 1;
    nb = (nb == 2) ? 0 : nb + 1;
  }
}

// 128x64 tile variant for O-proj: acc[4][2], 3 async16/thread (vmcnt(3)),
// 36 KB LDS triple-buffer -> 512 blocks, 2 blocks/CU (cross-block overlap
// that the old 256-block/1-per-CU oproj never had).
__device__ __forceinline__ void gemm_fast_core64(
    const unsigned short* __restrict__ A, const unsigned short* __restrict__ B,
    int tm, int tn, unsigned short* smem, f32x4 acc[4][2])
{
  const int t = threadIdx.x;
  const int lane = t & 63;
  const int w = t >> 6;
  const int wm = (w >> 1) * 64, wn = (w & 1) * 32;
  const int quad = lane >> 4, l16 = lane & 15;
  const int srow = lane >> 2;                          // 16 rows per async16
  const int scol = ((lane & 3) ^ ((lane >> 3) & 3)) * 8;  // swizzled src chunk
  const int xa = (l16 >> 1) & 3;                       // read-side swizzle key

#pragma unroll
  for (int mi = 0; mi < 4; ++mi)
#pragma unroll
    for (int ni = 0; ni < 2; ++ni)
      acc[mi][ni] = (f32x4){0.f, 0.f, 0.f, 0.f};

  // stage: A 128x32 (2 instr/thread) + B 64x32 (1 instr/thread)
  auto stage = [&](int f, int buf) {
    const int k0 = f * 32;
    unsigned short* dst = smem + buf * 6144;
#pragma unroll
    for (int i = 0; i < 2; ++i) {
      const int row = w * 32 + i * 16;
      async16(A + (size_t)(tm + row + srow) * D_MODEL + k0 + scol,
              dst + row * 32);
    }
    const int brow = w * 16;
    async16(B + (size_t)(tn + brow + srow) * D_MODEL + k0 + scol,
            dst + 4096 + brow * 32);
  };

  stage(0, 0);
  stage(1, 1);

  int cur = 0, nb = 2;
  for (int f = 0; f < 32; ++f) {
    if (f + 1 < 32) asm volatile("s_waitcnt vmcnt(3)" ::: "memory");
    else            asm volatile("s_waitcnt vmcnt(0)" ::: "memory");
    __builtin_amdgcn_s_barrier();            // raw: no forced vmcnt(0) drain
    __builtin_amdgcn_sched_barrier(0);       // pin LDS reads behind barrier
    if (f + 2 < 32) stage(f + 2, nb);
    const unsigned short* As = smem + cur * 6144;
    const unsigned short* Bs = As + 4096;
    bf16x8 af[4], bfv[2];
#pragma unroll
    for (int mi = 0; mi < 4; ++mi)
      af[mi] = *(const bf16x8*)(As + (wm + mi * 16 + l16) * 32 + (quad ^ xa) * 8);
#pragma unroll
    for (int ni = 0; ni < 2; ++ni)
      bfv[ni] = *(const bf16x8*)(Bs + (wn + ni * 16 + l16) * 32 + (quad ^ xa) * 8);
    __builtin_amdgcn_s_setprio(1);
#pragma unroll
    for (int mi = 0; mi < 4; ++mi)
#pragma unroll
      for (int ni = 0; ni < 2; ++ni)
        acc[mi][ni] = MFMA16(af[mi], bfv[ni], acc[mi][ni]);
    __builtin_amdgcn_s_setprio(0);
    cur = (cur == 2) ? 0 : cur + 1;
    nb = (nb == 2) ? 0 : nb + 1;
  }
}

// QKV fast: 1D grid 768. R7 partition: xcd (bid&7) owns M-chunk xcd*512
// (X panels XCD-local -> fetched once into that XCD's L2, 6-way reuse;
// was: X panels read from 4 XCDs = 4x HBM over-fetch, 29 MB vs 14 compulsory).
// s0 order: z slowest, tn mid, tm_local fastest -> first dispatch round works
// on one W z-slice (2 MB, L2-resident) across 4 X panels (1 MB).
__global__ __launch_bounds__(256) void qkv_fast_kernel(
    const unsigned short* __restrict__ X,
    const unsigned short* __restrict__ Wb,   // [3][1024][1024] bf16 (q,k,v)
    unsigned short* __restrict__ qd,
    unsigned short* __restrict__ kws,
    unsigned short* __restrict__ vws)
{
  __shared__ __align__(16) unsigned short smem[3 * 8192];  // 48 KB triple-buf
  const int bid = blockIdx.x;
  const int xcd = bid & 7, s0 = bid >> 3;      // s0 in 0..95
  const int z = s0 >> 5;                       // 0..2
  const int tn = ((s0 >> 2) & 7) * 128;
  const int tm = (xcd * 4 + (s0 & 3)) * 128;
  const unsigned short* W = Wb + (size_t)z * D_MODEL * D_MODEL;
  f32x4 acc[4][4];
  gemm_fast_core(X, W, tm, tn, smem, acc);

  const int t = threadIdx.x;
  const int lane = t & 63, w = t >> 6;
  const int wm = (w >> 1) * 64, wn = (w & 1) * 64;
  const int quad = lane >> 4, l16 = lane & 15;

  if (z == 2) {
    // V^T epilogue: LDS transpose repack (2 n-half passes) + coalesced stores.
    const int b = tm >> 11;
    const int sb = tm & 2047;
#pragma unroll
    for (int ph = 0; ph < 2; ++ph) {
      __syncthreads();
      if ((w & 1) == ph) {
#pragma unroll
        for (int mi = 0; mi < 4; ++mi)
#pragma unroll
          for (int ni = 0; ni < 4; ++ni)
#pragma unroll
            for (int r = 0; r < 4; ++r) {
              int m_local = wm + mi * 16 + quad * 4 + r;
              int n_sub = ni * 16 + l16;
              smem[n_sub * MST + m_local] = f2bf(acc[mi][ni][r]);
            }
      }
      __syncthreads();
      const int row = t >> 2, c0 = (t & 3) * 32;
      const int n_g = tn + ph * 64 + row;
      const int h = n_g >> 6, d = n_g & 63;
      unsigned short* dst = vws + (((size_t)b * NH + h) * HD + d) * SEQ + sb + c0;
#pragma unroll
      for (int cc = 0; cc < 4; ++cc)
        *(bf16x8*)(dst + cc * 8) = *(const bf16x8*)(smem + row * MST + c0 + cc * 8);
    }
    return;
  }
#pragma unroll
  for (int mi = 0; mi < 4; ++mi)
#pragma unroll
    for (int ni = 0; ni < 4; ++ni)
#pragma unroll
      for (int r = 0; r < 4; ++r) {
        int m = tm + wm + mi * 16 + quad * 4 + r;
        int n = tn + wn + ni * 16 + l16;
        unsigned short bv = f2bf(acc[mi][ni][r]);
        if (z == 0) {
          qd[(size_t)m * D_MODEL + n] = bv;
        } else {
          int b = m >> 11, sg = m & 2047;
          int h = n >> 6, d = n & 63;
          kws[(((size_t)b * NH + h) * SEQ + sg) * HD + d] = bv;
        }
      }
}

// O-proj fast: R7 grid 512 (128x64 tiles), 2 blocks/CU. Same M-chunk
// XCD partition: xcd owns rows xcd*512..+511.
__global__ __launch_bounds__(256) void oproj_fast_kernel(
    const unsigned short* __restrict__ AW,
    const unsigned short* __restrict__ Wo,
    float* __restrict__ tmp)
{
  __shared__ __align__(16) unsigned short smem[3 * 6144];  // 36 KB triple-buf
  const int bid = blockIdx.x;
  const int xcd = bid & 7, s0 = bid >> 3;      // s0 in 0..63
  const int tm = (xcd * 4 + (s0 >> 4)) * 128;
  const int tn = (s0 & 15) * 64;
  f32x4 acc[4][2];
  gemm_fast_core64(AW, Wo, tm, tn, smem, acc);

  const int t = threadIdx.x;
  const int lane = t & 63, w = t >> 6;
  const int wm = (w >> 1) * 64, wn = (w & 1) * 32;
  const int quad = lane >> 4, l16 = lane & 15;
#pragma unroll
  for (int mi = 0; mi < 4; ++mi)
#pragma unroll
    for (int ni = 0; ni < 2; ++ni)
#pragma unroll
      for (int r = 0; r < 4; ++r) {
        int m = tm + wm + mi * 16 + quad * 4 + r;
        int n = tn + wn + ni * 16 + l16;
        tmp[(size_t)m * D_MODEL + n] = acc[mi][ni][r];
      }
}

// ======================= SLOW PATH GEMM (dtype-adaptive) =======================
__device__ __forceinline__ void gemm_tile_128x128(
    const void* __restrict__ A, const void* __restrict__ B, int bf,
    int tm, int tn, unsigned short* As, unsigned short* Bs, f32x4 acc[4][4])
{
  const int t = threadIdx.x;
  const int lane = t & 63;
  const int w = t >> 6;
  const int wm = (w >> 1) * 64, wn = (w & 1) * 64;
  const int quad = lane >> 4, l16 = lane & 15;
  const int r0 = t >> 2, kc = (t & 3) * 8;
  const int r1 = r0 + 64;

#pragma unroll
  for (int mi = 0; mi < 4; ++mi)
#pragma unroll
    for (int ni = 0; ni < 4; ++ni)
      acc[mi][ni] = (f32x4){0.f, 0.f, 0.f, 0.f};

  for (int k0 = 0; k0 < D_MODEL; k0 += 32) {
    bf16x8 a0 = ld8(A, (size_t)(tm + r0) * D_MODEL + k0 + kc, bf);
    bf16x8 a1 = ld8(A, (size_t)(tm + r1) * D_MODEL + k0 + kc, bf);
    bf16x8 b0 = ld8(B, (size_t)(tn + r0) * D_MODEL + k0 + kc, bf);
    bf16x8 b1 = ld8(B, (size_t)(tn + r1) * D_MODEL + k0 + kc, bf);
    __syncthreads();
    *(bf16x8*)(As + r0 * LDA + kc) = a0;
    *(bf16x8*)(As + r1 * LDA + kc) = a1;
    *(bf16x8*)(Bs + r0 * LDA + kc) = b0;
    *(bf16x8*)(Bs + r1 * LDA + kc) = b1;
    __syncthreads();
    bf16x8 af[4], bfv[4];
#pragma unroll
    for (int mi = 0; mi < 4; ++mi)
      af[mi] = *(const bf16x8*)(As + (wm + mi * 16 + l16) * LDA + quad * 8);
#pragma unroll
    for (int ni = 0; ni < 4; ++ni)
      bfv[ni] = *(const bf16x8*)(Bs + (wn + ni * 16 + l16) * LDA + quad * 8);
#pragma unroll
    for (int mi = 0; mi < 4; ++mi)
#pragma unroll
      for (int ni = 0; ni < 4; ++ni)
        acc[mi][ni] = MFMA16(af[mi], bfv[ni], acc[mi][ni]);
  }
}

__global__ __launch_bounds__(256) void qkv_kernel(
    const void* __restrict__ X,
    const void* __restrict__ Wq,
    const void* __restrict__ Wk,
    const void* __restrict__ Wv,
    const int* __restrict__ flag,
    unsigned short* __restrict__ qd,
    unsigned short* __restrict__ kws,
    unsigned short* __restrict__ vws)
{
  __shared__ __align__(16) unsigned short As[128 * LDA];
  __shared__ __align__(16) unsigned short Bs[128 * LDA];
  const int bf = *flag;
  const int z = blockIdx.z;
  const void* W = (z == 0) ? Wq : ((z == 1) ? Wk : Wv);
  const int tm = blockIdx.y * 128, tn = blockIdx.x * 128;
  f32x4 acc[4][4];
  gemm_tile_128x128(X, W, bf, tm, tn, As, Bs, acc);

  const int t = threadIdx.x;
  const int lane = t & 63, w = t >> 6;
  const int wm = (w >> 1) * 64, wn = (w & 1) * 64;
  const int quad = lane >> 4, l16 = lane & 15;
#pragma unroll
  for (int mi = 0; mi < 4; ++mi)
#pragma unroll
    for (int ni = 0; ni < 4; ++ni)
#pragma unroll
      for (int r = 0; r < 4; ++r) {
        int m = tm + wm + mi * 16 + quad * 4 + r;
        int n = tn + wn + ni * 16 + l16;
        unsigned short bv = f2bf(acc[mi][ni][r]);
        if (z == 0) {
          qd[(size_t)m * D_MODEL + n] = bv;
        } else {
          int b = m >> 11, s = m & 2047;
          int h = n >> 6, d = n & 63;
          if (z == 1) kws[(((size_t)b * NH + h) * SEQ + s) * HD + d] = bv;
          else        vws[(((size_t)b * NH + h) * HD + d) * SEQ + s] = bv;
        }
      }
}

__global__ __launch_bounds__(256) void oproj_kernel(
    const unsigned short* __restrict__ AW,
    const void* __restrict__ Wo,
    const int* __restrict__ flag,
    float* __restrict__ tmp)
{
  __shared__ __align__(16) unsigned short As[128 * LDA];
  __shared__ __align__(16) unsigned short Bs[128 * LDA];
  const int bf = *flag;
  const int t = threadIdx.x;
  const int lane = t & 63;
  const int w = t >> 6;
  const int wm = (w >> 1) * 64, wn = (w & 1) * 64;
  const int quad = lane >> 4, l16 = lane & 15;
  const int r0 = t >> 2, kc = (t & 3) * 8;
  const int r1 = r0 + 64;
  const int tm = blockIdx.y * 128, tn = blockIdx.x * 128;
  f32x4 acc[4][4];
#pragma unroll
  for (int mi = 0; mi < 4; ++mi)
#pragma unroll
    for (int ni = 0; ni < 4; ++ni)
      acc[mi][ni] = (f32x4){0.f, 0.f, 0.f, 0.f};

  for (int k0 = 0; k0 < D_MODEL; k0 += 32) {
    bf16x8 a0 = *(const bf16x8*)(AW + (size_t)(tm + r0) * D_MODEL + k0 + kc);
    bf16x8 a1 = *(const bf16x8*)(AW + (size_t)(tm + r1) * D_MODEL + k0 + kc);
    bf16x8 b0 = ld8(Wo, (size_t)(tn + r0) * D_MODEL + k0 + kc, bf);
    bf16x8 b1 = ld8(Wo, (size_t)(tn + r1) * D_MODEL + k0 + kc, bf);
    __syncthreads();
    *(bf16x8*)(As + r0 * LDA + kc) = a0;
    *(bf16x8*)(As + r1 * LDA + kc) = a1;
    *(bf16x8*)(Bs + r0 * LDA + kc) = b0;
    *(bf16x8*)(Bs + r1 * LDA + kc) = b1;
    __syncthreads();
    bf16x8 af[4], bfv[4];
#pragma unroll
    for (int mi = 0; mi < 4; ++mi)
      af[mi] = *(const bf16x8*)(As + (wm + mi * 16 + l16) * LDA + quad * 8);
#pragma unroll
    for (int ni = 0; ni < 4; ++ni)
      bfv[ni] = *(const bf16x8*)(Bs + (wn + ni * 16 + l16) * LDA + quad * 8);
#pragma unroll
    for (int mi = 0; mi < 4; ++mi)
#pragma unroll
      for (int ni = 0; ni < 4; ++ni)
        acc[mi][ni] = MFMA16(af[mi], bfv[ni], acc[mi][ni]);
  }
#pragma unroll
  for (int mi = 0; mi < 4; ++mi)
#pragma unroll
    for (int ni = 0; ni < 4; ++ni)
#pragma unroll
      for (int r = 0; r < 4; ++r) {
        int m = tm + wm + mi * 16 + quad * 4 + r;
        int n = tn + wn + ni * 16 + l16;
        tmp[(size_t)m * D_MODEL + n] = acc[mi][ni][r];
      }
}

// ======================= Flash attention (shared-KV paired tiles) =======
// 512 blocks x 256 thr (4 waves, 2 waves/SIMD). Block owns q-tiles
// tA=31-p and tB=p (causal; non-causal 2p/2p+1). B's kv range 0..p is a
// PREFIX of A's 0..31-p: iterate kv ONCE over A's range, compute both tiles
// per item while kv <= p. 16 K/V ds_read_b128 fragments shared by both
// tiles; QK_A and QK_B issue back-to-back (cross-tile dep break).
// TRIPLE-BUFFERED depth-2 prefetch, counted vmcnt(4) + RAW s_barrier.
// K rows staged sigma-PERMUTED so S^T C-layout == PV B-operand layout; P is
// lane-local (cvt_pk pack), no LDS round-trip.
__device__ __forceinline__ void qk_part(
    const bf16x8 (&kfr)[4][2], const bf16x8 (&aq)[2], f32x4 (&sc)[4])
{
  __builtin_amdgcn_s_setprio(1);
#pragma unroll
  for (int cb = 0; cb < 4; ++cb) {
    sc[cb] = (f32x4){0.f, 0.f, 0.f, 0.f};
    sc[cb] = MFMA16(kfr[cb][0], aq[0], sc[cb]);
    sc[cb] = MFMA16(kfr[cb][1], aq[1], sc[cb]);
  }
  __builtin_amdgcn_s_setprio(0);
}

__device__ __forceinline__ void smpv_part(
    f32x4 (&sc)[4], const bf16x8 (&vfr)[4][2], f32x4 (&oacc)[4], float& lsum,
    int diag, int ktbase, int qq, int quad, float Cs)
{
  if (diag) {
#pragma unroll
    for (int cb = 0; cb < 4; ++cb)
#pragma unroll
      for (int rr = 0; rr < 4; ++rr)
        if (ktbase + (cb & 1) * 32 + quad * 8 + (cb >> 1) * 4 + rr > qq)
          sc[cb][rr] = NEG_BIG;
  }
  // no-max softmax: p = exp2(s*Cs); masked -> exp2(-huge) = 0
#pragma unroll
  for (int cb = 0; cb < 4; ++cb)
#pragma unroll
    for (int rr = 0; rr < 4; ++rr)
      sc[cb][rr] = __builtin_amdgcn_exp2f(sc[cb][rr] * Cs);
  // pairwise-tree row-sum (log depth)
  f32x4 t0, t1;
#pragma unroll
  for (int rr = 0; rr < 4; ++rr) { t0[rr] = sc[0][rr] + sc[1][rr]; }
#pragma unroll
  for (int rr = 0; rr < 4; ++rr) { t1[rr] = sc[2][rr] + sc[3][rr]; }
#pragma unroll
  for (int rr = 0; rr < 4; ++rr) { t0[rr] += t1[rr]; }
  lsum += (t0[0] + t0[1]) + (t0[2] + t0[3]);
  // lane-local pack: bp[hf] elems j=0..3 <- sc[hf], j=4..7 <- sc[2+hf]
  bf16x8 bp[2];
#pragma unroll
  for (int hf = 0; hf < 2; ++hf) {
    union { unsigned int w4[4]; bf16x8 v; } u;
    u.w4[0] = cvtpk_bf16(sc[hf][0], sc[hf][1]);
    u.w4[1] = cvtpk_bf16(sc[hf][2], sc[hf][3]);
    u.w4[2] = cvtpk_bf16(sc[2 + hf][0], sc[2 + hf][1]);
    u.w4[3] = cvtpk_bf16(sc[2 + hf][2], sc[2 + hf][3]);
    bp[hf] = u.v;
  }
  // O^T += V^T · P^T : C col = q, row = d
  __builtin_amdgcn_s_setprio(1);
#pragma unroll
  for (int db = 0; db < 4; ++db) {
    oacc[db] = MFMA16(vfr[db][0], bp[0], oacc[db]);
    oacc[db] = MFMA16(vfr[db][1], bp[1], oacc[db]);
  }
  __builtin_amdgcn_s_setprio(0);
}

__global__ __launch_bounds__(256, 2) void attn_kernel(
    unsigned short* __restrict__ Qd,   // Q in (plain [m,n]), attn-out in place
    const unsigned short* __restrict__ Kb,
    const unsigned short* __restrict__ Vt,
    const int* __restrict__ causal_p)
{
  __shared__ __align__(16) unsigned short Ks[3][64 * 64];
  __shared__ __align__(16) unsigned short Vs[3][64 * 64];
  const int bid = blockIdx.x;
  const int xcd = bid & 7, slot = bid >> 3;     // 512 blocks -> 64 slots/xcd
  const int bhl = slot >> 4, p = slot & 15;     // 4 bh x 16 pairs per xcd
  const int bh = xcd * 4 + bhl;
  const int b = bh >> 4, h = bh & 15;
  const int t = threadIdx.x, lane = t & 63, w = t >> 6;   // w in {0..3}
  const int quad = lane >> 4, l16 = lane & 15;
  const int causal = *causal_p;
  const int tA = causal ? (31 - p) : (2 * p);
  const int tB = causal ? p : (2 * p + 1);
  const int ITEMS = causal ? (32 - p) : 32;     // kv tiles for A (superset)
  unsigned short* qh = Qd + (size_t)b * SEQ * D_MODEL + h * HD;  // row stride D_MODEL
  const unsigned short* kh = Kb + ((size_t)b * NH + h) * SEQ * HD;
  const unsigned short* vh = Vt + ((size_t)b * NH + h) * HD * SEQ;
  const float Cs = 0.125f * 1.4426950408889634f;  // scale * log2(e)
  const int srow = lane >> 3;                     // staging: 8 rows / instr
  const int gcol = ((lane & 7) ^ srow) * 8;       // swizzled global chunk
  const int xa = l16 & 7;                         // read-side swizzle key

  // per-lane permuted K source rows for the two K staging instructions
  int kvp[2];
#pragma unroll
  for (int j2 = 0; j2 < 2; ++j2) {
    const int rp = w * 16 + j2 * 8 + srow;
    kvp[j2] = ((rp >> 4) & 1) * 32 + ((rp >> 2) & 3) * 8 + ((rp >> 5) & 1) * 4 + (rp & 3);
  }

  // Q fragments: wave w owns the 16-row strip tile*64 + w*16
  const int qA = tA * 64 + w * 16, qB = tB * 64 + w * 16;
  bf16x8 aqA[2], aqB[2];
#pragma unroll
  for (int ch = 0; ch < 2; ++ch) {
    aqA[ch] = *(const bf16x8*)(qh + (size_t)(qA + l16) * D_MODEL +
                               ch * 32 + quad * 8);
    aqB[ch] = *(const bf16x8*)(qh + (size_t)(qB + l16) * D_MODEL +
                               ch * 32 + quad * 8);
  }

  f32x4 oaccA[4], oaccB[4];
#pragma unroll
  for (int db = 0; db < 4; ++db) {
    oaccA[db] = (f32x4){0.f, 0.f, 0.f, 0.f};
    oaccB[db] = (f32x4){0.f, 0.f, 0.f, 0.f};
  }
  float lsumA = 0.f, lsumB = 0.f;

  // staging: 4 async16 per thread per item (2 K permuted + 2 V natural);
  // 4 waves cover all 64 LDS rows of each tile. kv tile index == item f.
  auto stage = [&](int f, int buf) {
#pragma unroll
    for (int j2 = 0; j2 < 2; ++j2) {
      const int row = w * 16 + j2 * 8;
      async16(kh + (size_t)(f * 64 + kvp[j2]) * HD + gcol, &Ks[buf][row * 64]);
      async16(vh + (size_t)(row + srow) * SEQ + f * 64 + gcol, &Vs[buf][row * 64]);
    }
  };

  // prologue: Q loads above (4 vmcnt), then batches 0,1 (4 each)
  stage(0, 0);
  if (ITEMS > 1) stage(1, 1);

  int cur = 0, nb = 2;
  for (int f = 0; f < ITEMS; ++f) {
    // wait: batch f landed (own loads); newest batch may stay in flight
    if (f + 1 < ITEMS) asm volatile("s_waitcnt vmcnt(4)" ::: "memory");
    else               asm volatile("s_waitcnt vmcnt(0)" ::: "memory");
    __builtin_amdgcn_s_barrier();            // raw: no forced vmcnt(0) drain
    __builtin_amdgcn_sched_barrier(0);       // pin LDS reads behind barrier
    if (f + 2 < ITEMS) stage(f + 2, nb);

    // shared K/V fragments (read once, used by both tiles)
    bf16x8 kfr[4][2], vfr[4][2];
#pragma unroll
    for (int cb = 0; cb < 4; ++cb)
#pragma unroll
      for (int hf = 0; hf < 2; ++hf) {
        kfr[cb][hf] = *(const bf16x8*)(&Ks[cur][(cb * 16 + l16) * 64 +
                                               ((hf * 4 + quad) ^ xa) * 8]);
        vfr[cb][hf] = *(const bf16x8*)(&Vs[cur][(cb * 16 + l16) * 64 +
                                               ((hf * 4 + quad) ^ xa) * 8]);
      }
    const int bAct = causal ? (f <= p) : 1;
    f32x4 scA[4], scB[4];
    qk_part(kfr, aqA, scA);
    if (bAct) qk_part(kfr, aqB, scB);       // B's MFMAs drain under A's softmax
    smpv_part(scA, vfr, oaccA, lsumA,
              causal && (f == ITEMS - 1), f * 64, qA + l16, quad, Cs);
    if (bAct)
      smpv_part(scB, vfr, oaccB, lsumB,
                causal && (f == p), f * 64, qB + l16, quad, Cs);
    cur = (cur == 2) ? 0 : cur + 1;
    nb = (nb == 2) ? 0 : nb + 1;
  }

  // epilogue per tile: reduce lsum over quads, write packed bf16 in place
  {
    float l = lsumA;
    l += __shfl_xor(l, 16, 64);
    l += __shfl_xor(l, 32, 64);
    float inv = 1.0f / l;
#pragma unroll
    for (int db = 0; db < 4; ++db) {
      u16x4 o;
#pragma unroll
      for (int rr = 0; rr < 4; ++rr) o[rr] = f2bf(oaccA[db][rr] * inv);
      *(u16x4*)(qh + (size_t)(qA + l16) * D_MODEL + db * 16 + quad * 4) = o;
    }
  }
  {
    float l = lsumB;
    l += __shfl_xor(l, 16, 64);
    l += __shfl_xor(l, 32, 64);
    float inv = 1.0f / l;
#pragma unroll
    for (int db = 0; db < 4; ++db) {
      u16x4 o;
#pragma unroll
      for (int rr = 0; rr < 4; ++rr) o[rr] = f2bf(oaccB[db][rr] * inv);
      *(u16x4*)(qh + (size_t)(qB + l16) * D_MODEL + db * 16 + quad * 4) = o;
    }
  }
}

// ---- final: d_out <- tmp, dtype per detected flag ----
__global__ __launch_bounds__(256) void final_kernel(
    const float* __restrict__ tmp, void* __restrict__ out,
    const int* __restrict__ flag)
{
  const int bf = *flag;
  size_t i = ((size_t)blockIdx.x * 256 + threadIdx.x) * 8;
  f32x4 lo = *(const f32x4*)(tmp + i);
  f32x4 hi = *(const f32x4*)(tmp + i + 4);
  if (bf) {
    bf16x8 r;
    r[0] = (short)f2bf(lo[0]); r[1] = (short)f2bf(lo[1]);
    r[2] = (short)f2bf(lo[2]); r[3] = (short)f2bf(lo[3]);
    r[4] = (short)f2bf(hi[0]); r[5] = (short)f2bf(hi[1]);
    r[6] = (short)f2bf(hi[2]); r[7] = (short)f2bf(hi[3]);
    *(bf16x8*)((unsigned short*)out + i) = r;
  } else {
    *(f32x4*)((float*)out + i) = lo;
    *(f32x4*)((float*)out + i + 4) = hi;
  }
}

extern "C" void kernel_launch(void* const* d_in, const int* in_sizes, int n_in,
                              void* d_out, int out_size, void* d_ws, size_t ws_size,
                              hipStream_t stream) {
  const void* X  = d_in[0];
  const void* Wq = d_in[1];
  const void* Wk = d_in[2];
  const void* Wv = d_in[3];
  const void* Wo = d_in[4];
  const int* causal = (const int*)d_in[5];

  const size_t NE = (size_t)2 * SEQ * D_MODEL;   // 4,194,304 elems
  const size_t WE = (size_t)D_MODEL * D_MODEL;   // 1,048,576 elems
  int* flag0 = (int*)d_ws;
  unsigned short* kws = (unsigned short*)((char*)d_ws + 64);  // K  [b,h,s,d]  8MB
  unsigned short* vws = kws + NE;                             // V^T [b,h,d,s] 8MB
  float* tmp = (float*)kws;                                   // 16MB over dead K+V
  unsigned short* Wb = vws + NE;                              // 4x bf16 W, 8MB
  unsigned short* qd = (unsigned short*)d_out;                // Q bf16, lower 8MB
  unsigned short* Xb = qd + NE;                               // X bf16, upper 8MB (f32 out)

  const bool big = ws_size >= (size_t)64 + 24ull * 1024 * 1024;

  hipLaunchKernelGGL(detect_kernel, dim3(1), dim3(64), 0, stream,
                     (const unsigned short*)X, flag0);
  if (big) {
    hipLaunchKernelGGL(convert_kernel, dim3(2048, 5), dim3(256), 0, stream,
                       X, Wq, Wk, Wv, Wo, flag0, Xb, Wb);
    hipLaunchKernelGGL(qkv_fast_kernel, dim3(768), dim3(256), 0, stream,
                       Xb, Wb, qd, kws, vws);
    hipLaunchKernelGGL(attn_kernel, dim3(512), dim3(256), 0, stream,
                       qd, kws, vws, causal);
    hipLaunchKernelGGL(oproj_fast_kernel, dim3(512), dim3(256), 0, stream,
                       qd, Wb + 3 * WE, tmp);
  } else {
    hipLaunchKernelGGL(qkv_kernel, dim3(8, 32, 3), dim3(256), 0, stream,
                       X, Wq, Wk, Wv, flag0, qd, kws, vws);
    hipLaunchKernelGGL(attn_kernel, dim3(512), dim3(256), 0, stream,
                       qd, kws, vws, causal);
    hipLaunchKernelGGL(oproj_kernel, dim3(8, 32), dim3(256), 0, stream,
                       qd, Wo, flag0, tmp);
  }
  hipLaunchKernelGGL(final_kernel, dim3(2048), dim3(256), 0, stream,
                     tmp, d_out, flag0);
}

// Round 8
// 172.650 us; speedup vs baseline: 1.0532x; 1.0532x over previous
//
#include <hip/hip_runtime.h>

typedef __attribute__((ext_vector_type(8))) short bf16x8;
typedef __attribute__((ext_vector_type(4))) float f32x4;
typedef __attribute__((ext_vector_type(4))) unsigned short u16x4;

#define MFMA16(a, b, c) __builtin_amdgcn_mfma_f32_16x16x32_bf16((a), (b), (c), 0, 0, 0)

static constexpr int D_MODEL = 1024;
static constexpr int SEQ = 2048;
static constexpr int NH = 16;
static constexpr int HD = 64;
static constexpr int LDA = 40;   // slow-path GEMM LDS row stride
static constexpr int MST = 136;  // V^T repack LDS row stride (elems)
static constexpr float NEG_BIG = -1.0e30f;

__device__ __forceinline__ unsigned short f2bf(float f) {
  union { float f; unsigned int u; } v; v.f = f;
  unsigned int r = v.u + 0x7fffu + ((v.u >> 16) & 1u);
  return (unsigned short)(r >> 16);
}

// packed f32x2 -> bf16x2 (RNE), one VALU op
__device__ __forceinline__ unsigned int cvtpk_bf16(float a, float b) {
  unsigned int r;
  asm("v_cvt_pk_bf16_f32 %0, %1, %2" : "=v"(r) : "v"(a), "v"(b));
  return r;
}

// Adaptive 8-element load: bf16 direct, or f32 -> RNE bf16 convert (slow path).
__device__ __forceinline__ bf16x8 ld8(const void* p, size_t eidx, int bf) {
  if (bf) return *(const bf16x8*)((const unsigned short*)p + eidx);
  const float* f = (const float*)p + eidx;
  f32x4 lo = *(const f32x4*)f;
  f32x4 hi = *(const f32x4*)(f + 4);
  bf16x8 r;
  r[0] = (short)f2bf(lo[0]); r[1] = (short)f2bf(lo[1]);
  r[2] = (short)f2bf(lo[2]); r[3] = (short)f2bf(lo[3]);
  r[4] = (short)f2bf(hi[0]); r[5] = (short)f2bf(hi[1]);
  r[6] = (short)f2bf(hi[2]); r[7] = (short)f2bf(hi[3]);
  return r;
}

// async global -> LDS, 16B per lane (dst = wave-uniform base + lane*16)
__device__ __forceinline__ void async16(const unsigned short* g, unsigned short* l) {
  __builtin_amdgcn_global_load_lds(
      (const __attribute__((address_space(1))) void*)g,
      (__attribute__((address_space(3))) void*)l, 16, 0, 0);
}

// ---- dtype detector ----
__global__ __launch_bounds__(64) void detect_kernel(
    const unsigned short* __restrict__ xs, int* __restrict__ flag) {
  int lane = threadIdx.x;
  unsigned short s = xs[2 * lane];
  int e = (s >> 7) & 0xFF;
  bool hit = (e >= 117 && e <= 129);
  unsigned long long m = __ballot(hit);
  if (lane == 0) { flag[0] = (__popcll(m) >= 32) ? 1 : 0; flag[1] = 1; }
}

// ---- pre-convert X and the four W matrices to bf16 (fast path) ----
__global__ __launch_bounds__(256) void convert_kernel(
    const void* __restrict__ X,
    const void* __restrict__ W0, const void* __restrict__ W1,
    const void* __restrict__ W2, const void* __restrict__ W3,
    const int* __restrict__ flag,
    unsigned short* __restrict__ Xb, unsigned short* __restrict__ Wb)
{
  const int bf = *flag;
  const int ty = blockIdx.y;
  const void* src; unsigned short* dst; size_t n;
  if (ty == 0) { src = X; dst = Xb; n = (size_t)2 * SEQ * D_MODEL; }
  else {
    src = (ty == 1) ? W0 : (ty == 2) ? W1 : (ty == 3) ? W2 : W3;
    dst = Wb + (size_t)(ty - 1) * D_MODEL * D_MODEL;
    n = (size_t)D_MODEL * D_MODEL;
  }
  size_t i = ((size_t)blockIdx.x * 256 + threadIdx.x) * 8;
  if (i >= n) return;
  *(bf16x8*)(dst + i) = ld8(src, i, bf);
}

// ======================= FAST PATH bf16 GEMM =======================
// 128x128 tile, BK=32, TRIPLE-BUFFERED depth-2 prefetch (attn-validated
// schedule): stage item f+2 each iter; counted vmcnt(4) wait + raw s_barrier
// -> each stage gets ~2 compute phases to land. 48 KB LDS -> 3 blocks/CU.
// Swizzle (32-elem rows): LDS[r][c] = G[r][c ^ ((r>>1)&3)].
__device__ __forceinline__ void gemm_fast_core(
    const unsigned short* __restrict__ A, const unsigned short* __restrict__ B,
    int tm, int tn, unsigned short* smem, f32x4 acc[4][4])
{
  const int t = threadIdx.x;
  const int lane = t & 63;
  const int w = t >> 6;
  const int wm = (w >> 1) * 64, wn = (w & 1) * 64;
  const int quad = lane >> 4, l16 = lane & 15;
  const int srow = lane >> 2;                          // 16 rows per async16
  const int scol = ((lane & 3) ^ ((lane >> 3) & 3)) * 8;  // swizzled src chunk
  const int xa = (l16 >> 1) & 3;                       // read-side swizzle key

#pragma unroll
  for (int mi = 0; mi < 4; ++mi)
#pragma unroll
    for (int ni = 0; ni < 4; ++ni)
      acc[mi][ni] = (f32x4){0.f, 0.f, 0.f, 0.f};

  // stage K-tile f (32 wide) into buffer buf: 4 async16 per thread
  auto stage = [&](int f, int buf) {
    const int k0 = f * 32;
    unsigned short* dst = smem + buf * 8192;
#pragma unroll
    for (int i = 0; i < 2; ++i) {
      const int row = w * 32 + i * 16;
      async16(A + (size_t)(tm + row + srow) * D_MODEL + k0 + scol,
              dst + row * 32);
      async16(B + (size_t)(tn + row + srow) * D_MODEL + k0 + scol,
              dst + 4096 + row * 32);
    }
  };

  stage(0, 0);
  stage(1, 1);

  int cur = 0, nb = 2;
  for (int f = 0; f < 32; ++f) {
    if (f + 1 < 32) asm volatile("s_waitcnt vmcnt(4)" ::: "memory");
    else            asm volatile("s_waitcnt vmcnt(0)" ::: "memory");
    __builtin_amdgcn_s_barrier();            // raw: no forced vmcnt(0) drain
    __builtin_amdgcn_sched_barrier(0);       // pin LDS reads behind barrier
    if (f + 2 < 32) stage(f + 2, nb);
    const unsigned short* As = smem + cur * 8192;
    const unsigned short* Bs = As + 4096;
    bf16x8 af[4], bfv[4];
#pragma unroll
    for (int mi = 0; mi < 4; ++mi)
      af[mi] = *(const bf16x8*)(As + (wm + mi * 16 + l16) * 32 + (quad ^ xa) * 8);
#pragma unroll
    for (int ni = 0; ni < 4; ++ni)
      bfv[ni] = *(const bf16x8*)(Bs + (wn + ni * 16 + l16) * 32 + (quad ^ xa) * 8);
    __builtin_amdgcn_s_setprio(1);
#pragma unroll
    for (int mi = 0; mi < 4; ++mi)
#pragma unroll
      for (int ni = 0; ni < 4; ++ni)
        acc[mi][ni] = MFMA16(af[mi], bfv[ni], acc[mi][ni]);
    __builtin_amdgcn_s_setprio(0);
    cur = (cur == 2) ? 0 : cur + 1;
    nb = (nb == 2) ? 0 : nb + 1;
  }
}

// 128x64 tile variant for O-proj: acc[4][2], 3 async16/thread (vmcnt(3)),
// 36 KB LDS triple-buffer -> 512 blocks, 2 blocks/CU.
__device__ __forceinline__ void gemm_fast_core64(
    const unsigned short* __restrict__ A, const unsigned short* __restrict__ B,
    int tm, int tn, unsigned short* smem, f32x4 acc[4][2])
{
  const int t = threadIdx.x;
  const int lane = t & 63;
  const int w = t >> 6;
  const int wm = (w >> 1) * 64, wn = (w & 1) * 32;
  const int quad = lane >> 4, l16 = lane & 15;
  const int srow = lane >> 2;                          // 16 rows per async16
  const int scol = ((lane & 3) ^ ((lane >> 3) & 3)) * 8;  // swizzled src chunk
  const int xa = (l16 >> 1) & 3;                       // read-side swizzle key

#pragma unroll
  for (int mi = 0; mi < 4; ++mi)
#pragma unroll
    for (int ni = 0; ni < 2; ++ni)
      acc[mi][ni] = (f32x4){0.f, 0.f, 0.f, 0.f};

  // stage: A 128x32 (2 instr/thread) + B 64x32 (1 instr/thread)
  auto stage = [&](int f, int buf) {
    const int k0 = f * 32;
    unsigned short* dst = smem + buf * 6144;
#pragma unroll
    for (int i = 0; i < 2; ++i) {
      const int row = w * 32 + i * 16;
      async16(A + (size_t)(tm + row + srow) * D_MODEL + k0 + scol,
              dst + row * 32);
    }
    const int brow = w * 16;
    async16(B + (size_t)(tn + brow + srow) * D_MODEL + k0 + scol,
            dst + 4096 + brow * 32);
  };

  stage(0, 0);
  stage(1, 1);

  int cur = 0, nb = 2;
  for (int f = 0; f < 32; ++f) {
    if (f + 1 < 32) asm volatile("s_waitcnt vmcnt(3)" ::: "memory");
    else            asm volatile("s_waitcnt vmcnt(0)" ::: "memory");
    __builtin_amdgcn_s_barrier();            // raw: no forced vmcnt(0) drain
    __builtin_amdgcn_sched_barrier(0);       // pin LDS reads behind barrier
    if (f + 2 < 32) stage(f + 2, nb);
    const unsigned short* As = smem + cur * 6144;
    const unsigned short* Bs = As + 4096;
    bf16x8 af[4], bfv[2];
#pragma unroll
    for (int mi = 0; mi < 4; ++mi)
      af[mi] = *(const bf16x8*)(As + (wm + mi * 16 + l16) * 32 + (quad ^ xa) * 8);
#pragma unroll
    for (int ni = 0; ni < 2; ++ni)
      bfv[ni] = *(const bf16x8*)(Bs + (wn + ni * 16 + l16) * 32 + (quad ^ xa) * 8);
    __builtin_amdgcn_s_setprio(1);
#pragma unroll
    for (int mi = 0; mi < 4; ++mi)
#pragma unroll
      for (int ni = 0; ni < 2; ++ni)
        acc[mi][ni] = MFMA16(af[mi], bfv[ni], acc[mi][ni]);
    __builtin_amdgcn_s_setprio(0);
    cur = (cur == 2) ? 0 : cur + 1;
    nb = (nb == 2) ? 0 : nb + 1;
  }
}

// QKV fast: 1D grid 768. XCD partition: xcd (bid&7) owns M-chunk xcd*512
// (X panels XCD-local). s0 order: z slowest, tn mid, tm_local fastest.
__global__ __launch_bounds__(256) void qkv_fast_kernel(
    const unsigned short* __restrict__ X,
    const unsigned short* __restrict__ Wb,   // [3][1024][1024] bf16 (q,k,v)
    unsigned short* __restrict__ qd,
    unsigned short* __restrict__ kws,
    unsigned short* __restrict__ vws)
{
  __shared__ __align__(16) unsigned short smem[3 * 8192];  // 48 KB triple-buf
  const int bid = blockIdx.x;
  const int xcd = bid & 7, s0 = bid >> 3;      // s0 in 0..95
  const int z = s0 >> 5;                       // 0..2
  const int tn = ((s0 >> 2) & 7) * 128;
  const int tm = (xcd * 4 + (s0 & 3)) * 128;
  const unsigned short* W = Wb + (size_t)z * D_MODEL * D_MODEL;
  f32x4 acc[4][4];
  gemm_fast_core(X, W, tm, tn, smem, acc);

  const int t = threadIdx.x;
  const int lane = t & 63, w = t >> 6;
  const int wm = (w >> 1) * 64, wn = (w & 1) * 64;
  const int quad = lane >> 4, l16 = lane & 15;

  if (z == 2) {
    // V^T epilogue: LDS transpose repack (2 n-half passes) + coalesced stores.
    const int b = tm >> 11;
    const int sb = tm & 2047;
#pragma unroll
    for (int ph = 0; ph < 2; ++ph) {
      __syncthreads();
      if ((w & 1) == ph) {
#pragma unroll
        for (int mi = 0; mi < 4; ++mi)
#pragma unroll
          for (int ni = 0; ni < 4; ++ni)
#pragma unroll
            for (int r = 0; r < 4; ++r) {
              int m_local = wm + mi * 16 + quad * 4 + r;
              int n_sub = ni * 16 + l16;
              smem[n_sub * MST + m_local] = f2bf(acc[mi][ni][r]);
            }
      }
      __syncthreads();
      const int row = t >> 2, c0 = (t & 3) * 32;
      const int n_g = tn + ph * 64 + row;
      const int h = n_g >> 6, d = n_g & 63;
      unsigned short* dst = vws + (((size_t)b * NH + h) * HD + d) * SEQ + sb + c0;
#pragma unroll
      for (int cc = 0; cc < 4; ++cc)
        *(bf16x8*)(dst + cc * 8) = *(const bf16x8*)(smem + row * MST + c0 + cc * 8);
    }
    return;
  }
#pragma unroll
  for (int mi = 0; mi < 4; ++mi)
#pragma unroll
    for (int ni = 0; ni < 4; ++ni)
#pragma unroll
      for (int r = 0; r < 4; ++r) {
        int m = tm + wm + mi * 16 + quad * 4 + r;
        int n = tn + wn + ni * 16 + l16;
        unsigned short bv = f2bf(acc[mi][ni][r]);
        if (z == 0) {
          qd[(size_t)m * D_MODEL + n] = bv;
        } else {
          int b = m >> 11, sg = m & 2047;
          int h = n >> 6, d = n & 63;
          kws[(((size_t)b * NH + h) * SEQ + sg) * HD + d] = bv;
        }
      }
}

// O-proj fast: grid 512 (128x64 tiles), 2 blocks/CU, M-chunk XCD partition.
// R8: writes DIRECTLY to d_out (dtype-branched) — qd no longer aliases
// d_out, so the tmp buffer and final_kernel pass are eliminated.
__global__ __launch_bounds__(256) void oproj_fast_kernel(
    const unsigned short* __restrict__ AW,
    const unsigned short* __restrict__ Wo,
    const int* __restrict__ flag,
    void* __restrict__ out)
{
  __shared__ __align__(16) unsigned short smem[3 * 6144];  // 36 KB triple-buf
  const int bf = *flag;
  const int bid = blockIdx.x;
  const int xcd = bid & 7, s0 = bid >> 3;      // s0 in 0..63
  const int tm = (xcd * 4 + (s0 >> 4)) * 128;
  const int tn = (s0 & 15) * 64;
  f32x4 acc[4][2];
  gemm_fast_core64(AW, Wo, tm, tn, smem, acc);

  const int t = threadIdx.x;
  const int lane = t & 63, w = t >> 6;
  const int wm = (w >> 1) * 64, wn = (w & 1) * 32;
  const int quad = lane >> 4, l16 = lane & 15;
  if (bf) {
    unsigned short* o = (unsigned short*)out;
#pragma unroll
    for (int mi = 0; mi < 4; ++mi)
#pragma unroll
      for (int ni = 0; ni < 2; ++ni)
#pragma unroll
        for (int r = 0; r < 4; ++r) {
          int m = tm + wm + mi * 16 + quad * 4 + r;
          int n = tn + wn + ni * 16 + l16;
          o[(size_t)m * D_MODEL + n] = f2bf(acc[mi][ni][r]);
        }
  } else {
    float* o = (float*)out;
#pragma unroll
    for (int mi = 0; mi < 4; ++mi)
#pragma unroll
      for (int ni = 0; ni < 2; ++ni)
#pragma unroll
        for (int r = 0; r < 4; ++r) {
          int m = tm + wm + mi * 16 + quad * 4 + r;
          int n = tn + wn + ni * 16 + l16;
          o[(size_t)m * D_MODEL + n] = acc[mi][ni][r];
        }
  }
}

// ======================= SLOW PATH GEMM (dtype-adaptive) =======================
__device__ __forceinline__ void gemm_tile_128x128(
    const void* __restrict__ A, const void* __restrict__ B, int bf,
    int tm, int tn, unsigned short* As, unsigned short* Bs, f32x4 acc[4][4])
{
  const int t = threadIdx.x;
  const int lane = t & 63;
  const int w = t >> 6;
  const int wm = (w >> 1) * 64, wn = (w & 1) * 64;
  const int quad = lane >> 4, l16 = lane & 15;
  const int r0 = t >> 2, kc = (t & 3) * 8;
  const int r1 = r0 + 64;

#pragma unroll
  for (int mi = 0; mi < 4; ++mi)
#pragma unroll
    for (int ni = 0; ni < 4; ++ni)
      acc[mi][ni] = (f32x4){0.f, 0.f, 0.f, 0.f};

  for (int k0 = 0; k0 < D_MODEL; k0 += 32) {
    bf16x8 a0 = ld8(A, (size_t)(tm + r0) * D_MODEL + k0 + kc, bf);
    bf16x8 a1 = ld8(A, (size_t)(tm + r1) * D_MODEL + k0 + kc, bf);
    bf16x8 b0 = ld8(B, (size_t)(tn + r0) * D_MODEL + k0 + kc, bf);
    bf16x8 b1 = ld8(B, (size_t)(tn + r1) * D_MODEL + k0 + kc, bf);
    __syncthreads();
    *(bf16x8*)(As + r0 * LDA + kc) = a0;
    *(bf16x8*)(As + r1 * LDA + kc) = a1;
    *(bf16x8*)(Bs + r0 * LDA + kc) = b0;
    *(bf16x8*)(Bs + r1 * LDA + kc) = b1;
    __syncthreads();
    bf16x8 af[4], bfv[4];
#pragma unroll
    for (int mi = 0; mi < 4; ++mi)
      af[mi] = *(const bf16x8*)(As + (wm + mi * 16 + l16) * LDA + quad * 8);
#pragma unroll
    for (int ni = 0; ni < 4; ++ni)
      bfv[ni] = *(const bf16x8*)(Bs + (wn + ni * 16 + l16) * LDA + quad * 8);
#pragma unroll
    for (int mi = 0; mi < 4; ++mi)
#pragma unroll
      for (int ni = 0; ni < 4; ++ni)
        acc[mi][ni] = MFMA16(af[mi], bfv[ni], acc[mi][ni]);
  }
}

__global__ __launch_bounds__(256) void qkv_kernel(
    const void* __restrict__ X,
    const void* __restrict__ Wq,
    const void* __restrict__ Wk,
    const void* __restrict__ Wv,
    const int* __restrict__ flag,
    unsigned short* __restrict__ qd,
    unsigned short* __restrict__ kws,
    unsigned short* __restrict__ vws)
{
  __shared__ __align__(16) unsigned short As[128 * LDA];
  __shared__ __align__(16) unsigned short Bs[128 * LDA];
  const int bf = *flag;
  const int z = blockIdx.z;
  const void* W = (z == 0) ? Wq : ((z == 1) ? Wk : Wv);
  const int tm = blockIdx.y * 128, tn = blockIdx.x * 128;
  f32x4 acc[4][4];
  gemm_tile_128x128(X, W, bf, tm, tn, As, Bs, acc);

  const int t = threadIdx.x;
  const int lane = t & 63, w = t >> 6;
  const int wm = (w >> 1) * 64, wn = (w & 1) * 64;
  const int quad = lane >> 4, l16 = lane & 15;
#pragma unroll
  for (int mi = 0; mi < 4; ++mi)
#pragma unroll
    for (int ni = 0; ni < 4; ++ni)
#pragma unroll
      for (int r = 0; r < 4; ++r) {
        int m = tm + wm + mi * 16 + quad * 4 + r;
        int n = tn + wn + ni * 16 + l16;
        unsigned short bv = f2bf(acc[mi][ni][r]);
        if (z == 0) {
          qd[(size_t)m * D_MODEL + n] = bv;
        } else {
          int b = m >> 11, s = m & 2047;
          int h = n >> 6, d = n & 63;
          if (z == 1) kws[(((size_t)b * NH + h) * SEQ + s) * HD + d] = bv;
          else        vws[(((size_t)b * NH + h) * HD + d) * SEQ + s] = bv;
        }
      }
}

__global__ __launch_bounds__(256) void oproj_kernel(
    const unsigned short* __restrict__ AW,
    const void* __restrict__ Wo,
    const int* __restrict__ flag,
    float* __restrict__ tmp)
{
  __shared__ __align__(16) unsigned short As[128 * LDA];
  __shared__ __align__(16) unsigned short Bs[128 * LDA];
  const int bf = *flag;
  const int t = threadIdx.x;
  const int lane = t & 63;
  const int w = t >> 6;
  const int wm = (w >> 1) * 64, wn = (w & 1) * 64;
  const int quad = lane >> 4, l16 = lane & 15;
  const int r0 = t >> 2, kc = (t & 3) * 8;
  const int r1 = r0 + 64;
  const int tm = blockIdx.y * 128, tn = blockIdx.x * 128;
  f32x4 acc[4][4];
#pragma unroll
  for (int mi = 0; mi < 4; ++mi)
#pragma unroll
    for (int ni = 0; ni < 4; ++ni)
      acc[mi][ni] = (f32x4){0.f, 0.f, 0.f, 0.f};

  for (int k0 = 0; k0 < D_MODEL; k0 += 32) {
    bf16x8 a0 = *(const bf16x8*)(AW + (size_t)(tm + r0) * D_MODEL + k0 + kc);
    bf16x8 a1 = *(const bf16x8*)(AW + (size_t)(tm + r1) * D_MODEL + k0 + kc);
    bf16x8 b0 = ld8(Wo, (size_t)(tn + r0) * D_MODEL + k0 + kc, bf);
    bf16x8 b1 = ld8(Wo, (size_t)(tn + r1) * D_MODEL + k0 + kc, bf);
    __syncthreads();
    *(bf16x8*)(As + r0 * LDA + kc) = a0;
    *(bf16x8*)(As + r1 * LDA + kc) = a1;
    *(bf16x8*)(Bs + r0 * LDA + kc) = b0;
    *(bf16x8*)(Bs + r1 * LDA + kc) = b1;
    __syncthreads();
    bf16x8 af[4], bfv[4];
#pragma unroll
    for (int mi = 0; mi < 4; ++mi)
      af[mi] = *(const bf16x8*)(As + (wm + mi * 16 + l16) * LDA + quad * 8);
#pragma unroll
    for (int ni = 0; ni < 4; ++ni)
      bfv[ni] = *(const bf16x8*)(Bs + (wn + ni * 16 + l16) * LDA + quad * 8);
#pragma unroll
    for (int mi = 0; mi < 4; ++mi)
#pragma unroll
      for (int ni = 0; ni < 4; ++ni)
        acc[mi][ni] = MFMA16(af[mi], bfv[ni], acc[mi][ni]);
  }
#pragma unroll
  for (int mi = 0; mi < 4; ++mi)
#pragma unroll
    for (int ni = 0; ni < 4; ++ni)
#pragma unroll
      for (int r = 0; r < 4; ++r) {
        int m = tm + wm + mi * 16 + quad * 4 + r;
        int n = tn + wn + ni * 16 + l16;
        tmp[(size_t)m * D_MODEL + n] = acc[mi][ni][r];
      }
}

// ======================= Flash attention (shared-KV paired tiles) =======
// 512 blocks x 256 thr (4 waves, 2 waves/SIMD). Block owns q-tiles
// tA=31-p and tB=p (causal; non-causal 2p/2p+1). B's kv range 0..p is a
// PREFIX of A's 0..31-p: iterate kv ONCE over A's range, compute both tiles
// per item while kv <= p. 16 K/V ds_read_b128 fragments shared by both
// tiles; QK_A and QK_B issue back-to-back (cross-tile dep break).
// TRIPLE-BUFFERED depth-2 prefetch, counted vmcnt(4) + RAW s_barrier.
// K rows staged sigma-PERMUTED so S^T C-layout == PV B-operand layout; P is
// lane-local (cvt_pk pack), no LDS round-trip.
__device__ __forceinline__ void qk_part(
    const bf16x8 (&kfr)[4][2], const bf16x8 (&aq)[2], f32x4 (&sc)[4])
{
  __builtin_amdgcn_s_setprio(1);
#pragma unroll
  for (int cb = 0; cb < 4; ++cb) {
    sc[cb] = (f32x4){0.f, 0.f, 0.f, 0.f};
    sc[cb] = MFMA16(kfr[cb][0], aq[0], sc[cb]);
    sc[cb] = MFMA16(kfr[cb][1], aq[1], sc[cb]);
  }
  __builtin_amdgcn_s_setprio(0);
}

__device__ __forceinline__ void smpv_part(
    f32x4 (&sc)[4], const bf16x8 (&vfr)[4][2], f32x4 (&oacc)[4], float& lsum,
    int diag, int ktbase, int qq, int quad, float Cs)
{
  if (diag) {
#pragma unroll
    for (int cb = 0; cb < 4; ++cb)
#pragma unroll
      for (int rr = 0; rr < 4; ++rr)
        if (ktbase + (cb & 1) * 32 + quad * 8 + (cb >> 1) * 4 + rr > qq)
          sc[cb][rr] = NEG_BIG;
  }
  // no-max softmax: p = exp2(s*Cs); masked -> exp2(-huge) = 0
#pragma unroll
  for (int cb = 0; cb < 4; ++cb)
#pragma unroll
    for (int rr = 0; rr < 4; ++rr)
      sc[cb][rr] = __builtin_amdgcn_exp2f(sc[cb][rr] * Cs);
  // pairwise-tree row-sum (log depth)
  f32x4 t0, t1;
#pragma unroll
  for (int rr = 0; rr < 4; ++rr) { t0[rr] = sc[0][rr] + sc[1][rr]; }
#pragma unroll
  for (int rr = 0; rr < 4; ++rr) { t1[rr] = sc[2][rr] + sc[3][rr]; }
#pragma unroll
  for (int rr = 0; rr < 4; ++rr) { t0[rr] += t1[rr]; }
  lsum += (t0[0] + t0[1]) + (t0[2] + t0[3]);
  // lane-local pack: bp[hf] elems j=0..3 <- sc[hf], j=4..7 <- sc[2+hf]
  bf16x8 bp[2];
#pragma unroll
  for (int hf = 0; hf < 2; ++hf) {
    union { unsigned int w4[4]; bf16x8 v; } u;
    u.w4[0] = cvtpk_bf16(sc[hf][0], sc[hf][1]);
    u.w4[1] = cvtpk_bf16(sc[hf][2], sc[hf][3]);
    u.w4[2] = cvtpk_bf16(sc[2 + hf][0], sc[2 + hf][1]);
    u.w4[3] = cvtpk_bf16(sc[2 + hf][2], sc[2 + hf][3]);
    bp[hf] = u.v;
  }
  // O^T += V^T · P^T : C col = q, row = d
  __builtin_amdgcn_s_setprio(1);
#pragma unroll
  for (int db = 0; db < 4; ++db) {
    oacc[db] = MFMA16(vfr[db][0], bp[0], oacc[db]);
    oacc[db] = MFMA16(vfr[db][1], bp[1], oacc[db]);
  }
  __builtin_amdgcn_s_setprio(0);
}

__global__ __launch_bounds__(256, 2) void attn_kernel(
    unsigned short* __restrict__ Qd,   // Q in (plain [m,n]), attn-out in place
    const unsigned short* __restrict__ Kb,
    const unsigned short* __restrict__ Vt,
    const int* __restrict__ causal_p)
{
  __shared__ __align__(16) unsigned short Ks[3][64 * 64];
  __shared__ __align__(16) unsigned short Vs[3][64 * 64];
  const int bid = blockIdx.x;
  const int xcd = bid & 7, slot = bid >> 3;     // 512 blocks -> 64 slots/xcd
  const int bhl = slot >> 4, p = slot & 15;     // 4 bh x 16 pairs per xcd
  const int bh = xcd * 4 + bhl;
  const int b = bh >> 4, h = bh & 15;
  const int t = threadIdx.x, lane = t & 63, w = t >> 6;   // w in {0..3}
  const int quad = lane >> 4, l16 = lane & 15;
  const int causal = *causal_p;
  const int tA = causal ? (31 - p) : (2 * p);
  const int tB = causal ? p : (2 * p + 1);
  const int ITEMS = causal ? (32 - p) : 32;     // kv tiles for A (superset)
  unsigned short* qh = Qd + (size_t)b * SEQ * D_MODEL + h * HD;  // row stride D_MODEL
  const unsigned short* kh = Kb + ((size_t)b * NH + h) * SEQ * HD;
  const unsigned short* vh = Vt + ((size_t)b * NH + h) * HD * SEQ;
  const float Cs = 0.125f * 1.4426950408889634f;  // scale * log2(e)
  const int srow = lane >> 3;                     // staging: 8 rows / instr
  const int gcol = ((lane & 7) ^ srow) * 8;       // swizzled global chunk
  const int xa = l16 & 7;                         // read-side swizzle key

  // per-lane permuted K source rows for the two K staging instructions
  int kvp[2];
#pragma unroll
  for (int j2 = 0; j2 < 2; ++j2) {
    const int rp = w * 16 + j2 * 8 + srow;
    kvp[j2] = ((rp >> 4) & 1) * 32 + ((rp >> 2) & 3) * 8 + ((rp >> 5) & 1) * 4 + (rp & 3);
  }

  // Q fragments: wave w owns the 16-row strip tile*64 + w*16
  const int qA = tA * 64 + w * 16, qB = tB * 64 + w * 16;
  bf16x8 aqA[2], aqB[2];
#pragma unroll
  for (int ch = 0; ch < 2; ++ch) {
    aqA[ch] = *(const bf16x8*)(qh + (size_t)(qA + l16) * D_MODEL +
                               ch * 32 + quad * 8);
    aqB[ch] = *(const bf16x8*)(qh + (size_t)(qB + l16) * D_MODEL +
                               ch * 32 + quad * 8);
  }

  f32x4 oaccA[4], oaccB[4];
#pragma unroll
  for (int db = 0; db < 4; ++db) {
    oaccA[db] = (f32x4){0.f, 0.f, 0.f, 0.f};
    oaccB[db] = (f32x4){0.f, 0.f, 0.f, 0.f};
  }
  float lsumA = 0.f, lsumB = 0.f;

  // staging: 4 async16 per thread per item (2 K permuted + 2 V natural);
  // 4 waves cover all 64 LDS rows of each tile. kv tile index == item f.
  auto stage = [&](int f, int buf) {
#pragma unroll
    for (int j2 = 0; j2 < 2; ++j2) {
      const int row = w * 16 + j2 * 8;
      async16(kh + (size_t)(f * 64 + kvp[j2]) * HD + gcol, &Ks[buf][row * 64]);
      async16(vh + (size_t)(row + srow) * SEQ + f * 64 + gcol, &Vs[buf][row * 64]);
    }
  };

  // prologue: Q loads above (4 vmcnt), then batches 0,1 (4 each)
  stage(0, 0);
  if (ITEMS > 1) stage(1, 1);

  int cur = 0, nb = 2;
  for (int f = 0; f < ITEMS; ++f) {
    // wait: batch f landed (own loads); newest batch may stay in flight
    if (f + 1 < ITEMS) asm volatile("s_waitcnt vmcnt(4)" ::: "memory");
    else               asm volatile("s_waitcnt vmcnt(0)" ::: "memory");
    __builtin_amdgcn_s_barrier();            // raw: no forced vmcnt(0) drain
    __builtin_amdgcn_sched_barrier(0);       // pin LDS reads behind barrier
    if (f + 2 < ITEMS) stage(f + 2, nb);

    // shared K/V fragments (read once, used by both tiles)
    bf16x8 kfr[4][2], vfr[4][2];
#pragma unroll
    for (int cb = 0; cb < 4; ++cb)
#pragma unroll
      for (int hf = 0; hf < 2; ++hf) {
        kfr[cb][hf] = *(const bf16x8*)(&Ks[cur][(cb * 16 + l16) * 64 +
                                               ((hf * 4 + quad) ^ xa) * 8]);
        vfr[cb][hf] = *(const bf16x8*)(&Vs[cur][(cb * 16 + l16) * 64 +
                                               ((hf * 4 + quad) ^ xa) * 8]);
      }
    const int bAct = causal ? (f <= p) : 1;
    f32x4 scA[4], scB[4];
    qk_part(kfr, aqA, scA);
    if (bAct) qk_part(kfr, aqB, scB);       // B's MFMAs drain under A's softmax
    smpv_part(scA, vfr, oaccA, lsumA,
              causal && (f == ITEMS - 1), f * 64, qA + l16, quad, Cs);
    if (bAct)
      smpv_part(scB, vfr, oaccB, lsumB,
                causal && (f == p), f * 64, qB + l16, quad, Cs);
    cur = (cur == 2) ? 0 : cur + 1;
    nb = (nb == 2) ? 0 : nb + 1;
  }

  // epilogue per tile: reduce lsum over quads, write packed bf16 in place
  {
    float l = lsumA;
    l += __shfl_xor(l, 16, 64);
    l += __shfl_xor(l, 32, 64);
    float inv = 1.0f / l;
#pragma unroll
    for (int db = 0; db < 4; ++db) {
      u16x4 o;
#pragma unroll
      for (int rr = 0; rr < 4; ++rr) o[rr] = f2bf(oaccA[db][rr] * inv);
      *(u16x4*)(qh + (size_t)(qA + l16) * D_MODEL + db * 16 + quad * 4) = o;
    }
  }
  {
    float l = lsumB;
    l += __shfl_xor(l, 16, 64);
    l += __shfl_xor(l, 32, 64);
    float inv = 1.0f / l;
#pragma unroll
    for (int db = 0; db < 4; ++db) {
      u16x4 o;
#pragma unroll
      for (int rr = 0; rr < 4; ++rr) o[rr] = f2bf(oaccB[db][rr] * inv);
      *(u16x4*)(qh + (size_t)(qB + l16) * D_MODEL + db * 16 + quad * 4) = o;
    }
  }
}

// ---- final: d_out <- tmp, dtype per detected flag (SLOW PATH ONLY) ----
__global__ __launch_bounds__(256) void final_kernel(
    const float* __restrict__ tmp, void* __restrict__ out,
    const int* __restrict__ flag)
{
  const int bf = *flag;
  size_t i = ((size_t)blockIdx.x * 256 + threadIdx.x) * 8;
  f32x4 lo = *(const f32x4*)(tmp + i);
  f32x4 hi = *(const f32x4*)(tmp + i + 4);
  if (bf) {
    bf16x8 r;
    r[0] = (short)f2bf(lo[0]); r[1] = (short)f2bf(lo[1]);
    r[2] = (short)f2bf(lo[2]); r[3] = (short)f2bf(lo[3]);
    r[4] = (short)f2bf(hi[0]); r[5] = (short)f2bf(hi[1]);
    r[6] = (short)f2bf(hi[2]); r[7] = (short)f2bf(hi[3]);
    *(bf16x8*)((unsigned short*)out + i) = r;
  } else {
    *(f32x4*)((float*)out + i) = lo;
    *(f32x4*)((float*)out + i + 4) = hi;
  }
}

extern "C" void kernel_launch(void* const* d_in, const int* in_sizes, int n_in,
                              void* d_out, int out_size, void* d_ws, size_t ws_size,
                              hipStream_t stream) {
  const void* X  = d_in[0];
  const void* Wq = d_in[1];
  const void* Wk = d_in[2];
  const void* Wv = d_in[3];
  const void* Wo = d_in[4];
  const int* causal = (const int*)d_in[5];

  const size_t NE = (size_t)2 * SEQ * D_MODEL;   // 4,194,304 elems
  const size_t WE = (size_t)D_MODEL * D_MODEL;   // 1,048,576 elems
  int* flag0 = (int*)d_ws;

  // fast path layout (all in ws; d_out untouched until oproj writes it):
  //   [64B flag][kws 8M][vws 8M][Wb 8M][qd 8M][Xb 8M]  = 40 MB + 64
  unsigned short* kws = (unsigned short*)((char*)d_ws + 64);
  unsigned short* vws = kws + NE;
  unsigned short* Wb  = vws + NE;
  unsigned short* qdf = Wb + 4 * WE;             // fast-path Q/attn buffer
  unsigned short* Xbf = qdf + NE;                // fast-path X bf16

  const bool big = ws_size >= (size_t)64 + 40ull * 1024 * 1024;

  hipLaunchKernelGGL(detect_kernel, dim3(1), dim3(64), 0, stream,
                     (const unsigned short*)X, flag0);
  if (big) {
    hipLaunchKernelGGL(convert_kernel, dim3(2048, 5), dim3(256), 0, stream,
                       X, Wq, Wk, Wv, Wo, flag0, Xbf, Wb);
    hipLaunchKernelGGL(qkv_fast_kernel, dim3(768), dim3(256), 0, stream,
                       Xbf, Wb, qdf, kws, vws);
    hipLaunchKernelGGL(attn_kernel, dim3(512), dim3(256), 0, stream,
                       qdf, kws, vws, causal);
    hipLaunchKernelGGL(oproj_fast_kernel, dim3(512), dim3(256), 0, stream,
                       qdf, Wb + 3 * WE, flag0, d_out);
    // no final_kernel: oproj wrote d_out directly (dtype-branched)
  } else {
    // slow path: legacy layout (qd aliases d_out; tmp over dead K/V)
    float* tmp = (float*)kws;
    unsigned short* qd = (unsigned short*)d_out;
    hipLaunchKernelGGL(qkv_kernel, dim3(8, 32, 3), dim3(256), 0, stream,
                       X, Wq, Wk, Wv, flag0, qd, kws, vws);
    hipLaunchKernelGGL(attn_kernel, dim3(512), dim3(256), 0, stream,
                       qd, kws, vws, causal);
    hipLaunchKernelGGL(oproj_kernel, dim3(8, 32), dim3(256), 0, stream,
                       qd, Wo, flag0, tmp);
    hipLaunchKernelGGL(final_kernel, dim3(2048), dim3(256), 0, stream,
                       tmp, d_out, flag0);
  }
}

// Round 9
// 172.154 us; speedup vs baseline: 1.0562x; 1.0029x over previous
//
#include <hip/hip_runtime.h>

typedef __attribute__((ext_vector_type(8))) short bf16x8;
typedef __attribute__((ext_vector_type(4))) float f32x4;
typedef __attribute__((ext_vector_type(4))) unsigned short u16x4;

#define MFMA16(a, b, c) __builtin_amdgcn_mfma_f32_16x16x32_bf16((a), (b), (c), 0, 0, 0)

static constexpr int D_MODEL = 1024;
static constexpr int SEQ = 2048;
static constexpr int NH = 16;
static constexpr int HD = 64;
static constexpr int LDA = 40;   // slow-path GEMM LDS row stride
static constexpr int MST = 136;  // V^T repack LDS row stride (elems)
static constexpr float NEG_BIG = -1.0e30f;

__device__ __forceinline__ unsigned short f2bf(float f) {
  union { float f; unsigned int u; } v; v.f = f;
  unsigned int r = v.u + 0x7fffu + ((v.u >> 16) & 1u);
  return (unsigned short)(r >> 16);
}

// packed f32x2 -> bf16x2 (RNE), one VALU op
__device__ __forceinline__ unsigned int cvtpk_bf16(float a, float b) {
  unsigned int r;
  asm("v_cvt_pk_bf16_f32 %0, %1, %2" : "=v"(r) : "v"(a), "v"(b));
  return r;
}

// Inline dtype scan (identical logic to detect_kernel): every wave reads the
// same 64 even-index u16 of X and votes; result is wave-uniform. ~128B, L2-hot.
__device__ __forceinline__ int detect_bf16(const unsigned short* xs, int lane) {
  unsigned short s = xs[2 * lane];
  int e = (s >> 7) & 0xFF;
  bool hit = (e >= 117 && e <= 129);
  unsigned long long m = __ballot(hit);
  return (__popcll(m) >= 32) ? 1 : 0;
}

// Adaptive 8-element load: bf16 direct, or f32 -> RNE bf16 convert (slow path).
__device__ __forceinline__ bf16x8 ld8(const void* p, size_t eidx, int bf) {
  if (bf) return *(const bf16x8*)((const unsigned short*)p + eidx);
  const float* f = (const float*)p + eidx;
  f32x4 lo = *(const f32x4*)f;
  f32x4 hi = *(const f32x4*)(f + 4);
  bf16x8 r;
  r[0] = (short)f2bf(lo[0]); r[1] = (short)f2bf(lo[1]);
  r[2] = (short)f2bf(lo[2]); r[3] = (short)f2bf(lo[3]);
  r[4] = (short)f2bf(hi[0]); r[5] = (short)f2bf(hi[1]);
  r[6] = (short)f2bf(hi[2]); r[7] = (short)f2bf(hi[3]);
  return r;
}

// async global -> LDS, 16B per lane (dst = wave-uniform base + lane*16)
__device__ __forceinline__ void async16(const unsigned short* g, unsigned short* l) {
  __builtin_amdgcn_global_load_lds(
      (const __attribute__((address_space(1))) void*)g,
      (__attribute__((address_space(3))) void*)l, 16, 0, 0);
}

// ---- dtype detector (SLOW PATH ONLY; fast path inlines the scan) ----
__global__ __launch_bounds__(64) void detect_kernel(
    const unsigned short* __restrict__ xs, int* __restrict__ flag) {
  int lane = threadIdx.x;
  unsigned short s = xs[2 * lane];
  int e = (s >> 7) & 0xFF;
  bool hit = (e >= 117 && e <= 129);
  unsigned long long m = __ballot(hit);
  if (lane == 0) { flag[0] = (__popcll(m) >= 32) ? 1 : 0; flag[1] = 1; }
}

// ---- pre-convert X and the four W matrices to bf16 (fast path) ----
// R9: dtype detected inline (no dependency on detect_kernel).
__global__ __launch_bounds__(256) void convert_kernel(
    const void* __restrict__ X,
    const void* __restrict__ W0, const void* __restrict__ W1,
    const void* __restrict__ W2, const void* __restrict__ W3,
    unsigned short* __restrict__ Xb, unsigned short* __restrict__ Wb)
{
  const int bf = detect_bf16((const unsigned short*)X, threadIdx.x & 63);
  const int ty = blockIdx.y;
  const void* src; unsigned short* dst; size_t n;
  if (ty == 0) { src = X; dst = Xb; n = (size_t)2 * SEQ * D_MODEL; }
  else {
    src = (ty == 1) ? W0 : (ty == 2) ? W1 : (ty == 3) ? W2 : W3;
    dst = Wb + (size_t)(ty - 1) * D_MODEL * D_MODEL;
    n = (size_t)D_MODEL * D_MODEL;
  }
  size_t i = ((size_t)blockIdx.x * 256 + threadIdx.x) * 8;
  if (i >= n) return;
  *(bf16x8*)(dst + i) = ld8(src, i, bf);
}

// ======================= FAST PATH bf16 GEMM =======================
// 128x128 tile, BK=32, TRIPLE-BUFFERED depth-2 prefetch (attn-validated
// schedule): stage item f+2 each iter; counted vmcnt(4) wait + raw s_barrier
// -> each stage gets ~2 compute phases to land. 48 KB LDS -> 3 blocks/CU.
// Swizzle (32-elem rows): LDS[r][c] = G[r][c ^ ((r>>1)&3)].
__device__ __forceinline__ void gemm_fast_core(
    const unsigned short* __restrict__ A, const unsigned short* __restrict__ B,
    int tm, int tn, unsigned short* smem, f32x4 acc[4][4])
{
  const int t = threadIdx.x;
  const int lane = t & 63;
  const int w = t >> 6;
  const int wm = (w >> 1) * 64, wn = (w & 1) * 64;
  const int quad = lane >> 4, l16 = lane & 15;
  const int srow = lane >> 2;                          // 16 rows per async16
  const int scol = ((lane & 3) ^ ((lane >> 3) & 3)) * 8;  // swizzled src chunk
  const int xa = (l16 >> 1) & 3;                       // read-side swizzle key

#pragma unroll
  for (int mi = 0; mi < 4; ++mi)
#pragma unroll
    for (int ni = 0; ni < 4; ++ni)
      acc[mi][ni] = (f32x4){0.f, 0.f, 0.f, 0.f};

  // stage K-tile f (32 wide) into buffer buf: 4 async16 per thread
  auto stage = [&](int f, int buf) {
    const int k0 = f * 32;
    unsigned short* dst = smem + buf * 8192;
#pragma unroll
    for (int i = 0; i < 2; ++i) {
      const int row = w * 32 + i * 16;
      async16(A + (size_t)(tm + row + srow) * D_MODEL + k0 + scol,
              dst + row * 32);
      async16(B + (size_t)(tn + row + srow) * D_MODEL + k0 + scol,
              dst + 4096 + row * 32);
    }
  };

  stage(0, 0);
  stage(1, 1);

  int cur = 0, nb = 2;
  for (int f = 0; f < 32; ++f) {
    if (f + 1 < 32) asm volatile("s_waitcnt vmcnt(4)" ::: "memory");
    else            asm volatile("s_waitcnt vmcnt(0)" ::: "memory");
    __builtin_amdgcn_s_barrier();            // raw: no forced vmcnt(0) drain
    __builtin_amdgcn_sched_barrier(0);       // pin LDS reads behind barrier
    if (f + 2 < 32) stage(f + 2, nb);
    const unsigned short* As = smem + cur * 8192;
    const unsigned short* Bs = As + 4096;
    bf16x8 af[4], bfv[4];
#pragma unroll
    for (int mi = 0; mi < 4; ++mi)
      af[mi] = *(const bf16x8*)(As + (wm + mi * 16 + l16) * 32 + (quad ^ xa) * 8);
#pragma unroll
    for (int ni = 0; ni < 4; ++ni)
      bfv[ni] = *(const bf16x8*)(Bs + (wn + ni * 16 + l16) * 32 + (quad ^ xa) * 8);
    __builtin_amdgcn_s_setprio(1);
#pragma unroll
    for (int mi = 0; mi < 4; ++mi)
#pragma unroll
      for (int ni = 0; ni < 4; ++ni)
        acc[mi][ni] = MFMA16(af[mi], bfv[ni], acc[mi][ni]);
    __builtin_amdgcn_s_setprio(0);
    cur = (cur == 2) ? 0 : cur + 1;
    nb = (nb == 2) ? 0 : nb + 1;
  }
}

// 128x64 tile variant for O-proj: acc[4][2], 3 async16/thread (vmcnt(3)),
// 36 KB LDS triple-buffer -> 512 blocks, 2 blocks/CU.
__device__ __forceinline__ void gemm_fast_core64(
    const unsigned short* __restrict__ A, const unsigned short* __restrict__ B,
    int tm, int tn, unsigned short* smem, f32x4 acc[4][2])
{
  const int t = threadIdx.x;
  const int lane = t & 63;
  const int w = t >> 6;
  const int wm = (w >> 1) * 64, wn = (w & 1) * 32;
  const int quad = lane >> 4, l16 = lane & 15;
  const int srow = lane >> 2;                          // 16 rows per async16
  const int scol = ((lane & 3) ^ ((lane >> 3) & 3)) * 8;  // swizzled src chunk
  const int xa = (l16 >> 1) & 3;                       // read-side swizzle key

#pragma unroll
  for (int mi = 0; mi < 4; ++mi)
#pragma unroll
    for (int ni = 0; ni < 2; ++ni)
      acc[mi][ni] = (f32x4){0.f, 0.f, 0.f, 0.f};

  // stage: A 128x32 (2 instr/thread) + B 64x32 (1 instr/thread)
  auto stage = [&](int f, int buf) {
    const int k0 = f * 32;
    unsigned short* dst = smem + buf * 6144;
#pragma unroll
    for (int i = 0; i < 2; ++i) {
      const int row = w * 32 + i * 16;
      async16(A + (size_t)(tm + row + srow) * D_MODEL + k0 + scol,
              dst + row * 32);
    }
    const int brow = w * 16;
    async16(B + (size_t)(tn + brow + srow) * D_MODEL + k0 + scol,
            dst + 4096 + brow * 32);
  };

  stage(0, 0);
  stage(1, 1);

  int cur = 0, nb = 2;
  for (int f = 0; f < 32; ++f) {
    if (f + 1 < 32) asm volatile("s_waitcnt vmcnt(3)" ::: "memory");
    else            asm volatile("s_waitcnt vmcnt(0)" ::: "memory");
    __builtin_amdgcn_s_barrier();            // raw: no forced vmcnt(0) drain
    __builtin_amdgcn_sched_barrier(0);       // pin LDS reads behind barrier
    if (f + 2 < 32) stage(f + 2, nb);
    const unsigned short* As = smem + cur * 6144;
    const unsigned short* Bs = As + 4096;
    bf16x8 af[4], bfv[2];
#pragma unroll
    for (int mi = 0; mi < 4; ++mi)
      af[mi] = *(const bf16x8*)(As + (wm + mi * 16 + l16) * 32 + (quad ^ xa) * 8);
#pragma unroll
    for (int ni = 0; ni < 2; ++ni)
      bfv[ni] = *(const bf16x8*)(Bs + (wn + ni * 16 + l16) * 32 + (quad ^ xa) * 8);
    __builtin_amdgcn_s_setprio(1);
#pragma unroll
    for (int mi = 0; mi < 4; ++mi)
#pragma unroll
      for (int ni = 0; ni < 2; ++ni)
        acc[mi][ni] = MFMA16(af[mi], bfv[ni], acc[mi][ni]);
    __builtin_amdgcn_s_setprio(0);
    cur = (cur == 2) ? 0 : cur + 1;
    nb = (nb == 2) ? 0 : nb + 1;
  }
}

// QKV fast: 1D grid 768. XCD partition: xcd (bid&7) owns M-chunk xcd*512
// (X panels XCD-local). s0 order: z slowest, tn mid, tm_local fastest.
__global__ __launch_bounds__(256) void qkv_fast_kernel(
    const unsigned short* __restrict__ X,
    const unsigned short* __restrict__ Wb,   // [3][1024][1024] bf16 (q,k,v)
    unsigned short* __restrict__ qd,
    unsigned short* __restrict__ kws,
    unsigned short* __restrict__ vws)
{
  __shared__ __align__(16) unsigned short smem[3 * 8192];  // 48 KB triple-buf
  const int bid = blockIdx.x;
  const int xcd = bid & 7, s0 = bid >> 3;      // s0 in 0..95
  const int z = s0 >> 5;                       // 0..2
  const int tn = ((s0 >> 2) & 7) * 128;
  const int tm = (xcd * 4 + (s0 & 3)) * 128;
  const unsigned short* W = Wb + (size_t)z * D_MODEL * D_MODEL;
  f32x4 acc[4][4];
  gemm_fast_core(X, W, tm, tn, smem, acc);

  const int t = threadIdx.x;
  const int lane = t & 63, w = t >> 6;
  const int wm = (w >> 1) * 64, wn = (w & 1) * 64;
  const int quad = lane >> 4, l16 = lane & 15;

  if (z == 2) {
    // V^T epilogue: LDS transpose repack (2 n-half passes) + coalesced stores.
    const int b = tm >> 11;
    const int sb = tm & 2047;
#pragma unroll
    for (int ph = 0; ph < 2; ++ph) {
      __syncthreads();
      if ((w & 1) == ph) {
#pragma unroll
        for (int mi = 0; mi < 4; ++mi)
#pragma unroll
          for (int ni = 0; ni < 4; ++ni)
#pragma unroll
            for (int r = 0; r < 4; ++r) {
              int m_local = wm + mi * 16 + quad * 4 + r;
              int n_sub = ni * 16 + l16;
              smem[n_sub * MST + m_local] = f2bf(acc[mi][ni][r]);
            }
      }
      __syncthreads();
      const int row = t >> 2, c0 = (t & 3) * 32;
      const int n_g = tn + ph * 64 + row;
      const int h = n_g >> 6, d = n_g & 63;
      unsigned short* dst = vws + (((size_t)b * NH + h) * HD + d) * SEQ + sb + c0;
#pragma unroll
      for (int cc = 0; cc < 4; ++cc)
        *(bf16x8*)(dst + cc * 8) = *(const bf16x8*)(smem + row * MST + c0 + cc * 8);
    }
    return;
  }
#pragma unroll
  for (int mi = 0; mi < 4; ++mi)
#pragma unroll
    for (int ni = 0; ni < 4; ++ni)
#pragma unroll
      for (int r = 0; r < 4; ++r) {
        int m = tm + wm + mi * 16 + quad * 4 + r;
        int n = tn + wn + ni * 16 + l16;
        unsigned short bv = f2bf(acc[mi][ni][r]);
        if (z == 0) {
          qd[(size_t)m * D_MODEL + n] = bv;
        } else {
          int b = m >> 11, sg = m & 2047;
          int h = n >> 6, d = n & 63;
          kws[(((size_t)b * NH + h) * SEQ + sg) * HD + d] = bv;
        }
      }
}

// O-proj fast: grid 512 (128x64 tiles), 2 blocks/CU, M-chunk XCD partition.
// Writes DIRECTLY to d_out (dtype-branched, detected inline from X).
__global__ __launch_bounds__(256) void oproj_fast_kernel(
    const unsigned short* __restrict__ AW,
    const unsigned short* __restrict__ Wo,
    const unsigned short* __restrict__ Xorig,   // for inline dtype detect
    void* __restrict__ out)
{
  __shared__ __align__(16) unsigned short smem[3 * 6144];  // 36 KB triple-buf
  const int bf = detect_bf16(Xorig, threadIdx.x & 63);
  const int bid = blockIdx.x;
  const int xcd = bid & 7, s0 = bid >> 3;      // s0 in 0..63
  const int tm = (xcd * 4 + (s0 >> 4)) * 128;
  const int tn = (s0 & 15) * 64;
  f32x4 acc[4][2];
  gemm_fast_core64(AW, Wo, tm, tn, smem, acc);

  const int t = threadIdx.x;
  const int lane = t & 63, w = t >> 6;
  const int wm = (w >> 1) * 64, wn = (w & 1) * 32;
  const int quad = lane >> 4, l16 = lane & 15;
  if (bf) {
    unsigned short* o = (unsigned short*)out;
#pragma unroll
    for (int mi = 0; mi < 4; ++mi)
#pragma unroll
      for (int ni = 0; ni < 2; ++ni)
#pragma unroll
        for (int r = 0; r < 4; ++r) {
          int m = tm + wm + mi * 16 + quad * 4 + r;
          int n = tn + wn + ni * 16 + l16;
          o[(size_t)m * D_MODEL + n] = f2bf(acc[mi][ni][r]);
        }
  } else {
    float* o = (float*)out;
#pragma unroll
    for (int mi = 0; mi < 4; ++mi)
#pragma unroll
      for (int ni = 0; ni < 2; ++ni)
#pragma unroll
        for (int r = 0; r < 4; ++r) {
          int m = tm + wm + mi * 16 + quad * 4 + r;
          int n = tn + wn + ni * 16 + l16;
          o[(size_t)m * D_MODEL + n] = acc[mi][ni][r];
        }
  }
}

// ======================= SLOW PATH GEMM (dtype-adaptive) =======================
__device__ __forceinline__ void gemm_tile_128x128(
    const void* __restrict__ A, const void* __restrict__ B, int bf,
    int tm, int tn, unsigned short* As, unsigned short* Bs, f32x4 acc[4][4])
{
  const int t = threadIdx.x;
  const int lane = t & 63;
  const int w = t >> 6;
  const int wm = (w >> 1) * 64, wn = (w & 1) * 64;
  const int quad = lane >> 4, l16 = lane & 15;
  const int r0 = t >> 2, kc = (t & 3) * 8;
  const int r1 = r0 + 64;

#pragma unroll
  for (int mi = 0; mi < 4; ++mi)
#pragma unroll
    for (int ni = 0; ni < 4; ++ni)
      acc[mi][ni] = (f32x4){0.f, 0.f, 0.f, 0.f};

  for (int k0 = 0; k0 < D_MODEL; k0 += 32) {
    bf16x8 a0 = ld8(A, (size_t)(tm + r0) * D_MODEL + k0 + kc, bf);
    bf16x8 a1 = ld8(A, (size_t)(tm + r1) * D_MODEL + k0 + kc, bf);
    bf16x8 b0 = ld8(B, (size_t)(tn + r0) * D_MODEL + k0 + kc, bf);
    bf16x8 b1 = ld8(B, (size_t)(tn + r1) * D_MODEL + k0 + kc, bf);
    __syncthreads();
    *(bf16x8*)(As + r0 * LDA + kc) = a0;
    *(bf16x8*)(As + r1 * LDA + kc) = a1;
    *(bf16x8*)(Bs + r0 * LDA + kc) = b0;
    *(bf16x8*)(Bs + r1 * LDA + kc) = b1;
    __syncthreads();
    bf16x8 af[4], bfv[4];
#pragma unroll
    for (int mi = 0; mi < 4; ++mi)
      af[mi] = *(const bf16x8*)(As + (wm + mi * 16 + l16) * LDA + quad * 8);
#pragma unroll
    for (int ni = 0; ni < 4; ++ni)
      bfv[ni] = *(const bf16x8*)(Bs + (wn + ni * 16 + l16) * LDA + quad * 8);
#pragma unroll
    for (int mi = 0; mi < 4; ++mi)
#pragma unroll
      for (int ni = 0; ni < 4; ++ni)
        acc[mi][ni] = MFMA16(af[mi], bfv[ni], acc[mi][ni]);
  }
}

__global__ __launch_bounds__(256) void qkv_kernel(
    const void* __restrict__ X,
    const void* __restrict__ Wq,
    const void* __restrict__ Wk,
    const void* __restrict__ Wv,
    const int* __restrict__ flag,
    unsigned short* __restrict__ qd,
    unsigned short* __restrict__ kws,
    unsigned short* __restrict__ vws)
{
  __shared__ __align__(16) unsigned short As[128 * LDA];
  __shared__ __align__(16) unsigned short Bs[128 * LDA];
  const int bf = *flag;
  const int z = blockIdx.z;
  const void* W = (z == 0) ? Wq : ((z == 1) ? Wk : Wv);
  const int tm = blockIdx.y * 128, tn = blockIdx.x * 128;
  f32x4 acc[4][4];
  gemm_tile_128x128(X, W, bf, tm, tn, As, Bs, acc);

  const int t = threadIdx.x;
  const int lane = t & 63, w = t >> 6;
  const int wm = (w >> 1) * 64, wn = (w & 1) * 64;
  const int quad = lane >> 4, l16 = lane & 15;
#pragma unroll
  for (int mi = 0; mi < 4; ++mi)
#pragma unroll
    for (int ni = 0; ni < 4; ++ni)
#pragma unroll
      for (int r = 0; r < 4; ++r) {
        int m = tm + wm + mi * 16 + quad * 4 + r;
        int n = tn + wn + ni * 16 + l16;
        unsigned short bv = f2bf(acc[mi][ni][r]);
        if (z == 0) {
          qd[(size_t)m * D_MODEL + n] = bv;
        } else {
          int b = m >> 11, s = m & 2047;
          int h = n >> 6, d = n & 63;
          if (z == 1) kws[(((size_t)b * NH + h) * SEQ + s) * HD + d] = bv;
          else        vws[(((size_t)b * NH + h) * HD + d) * SEQ + s] = bv;
        }
      }
}

__global__ __launch_bounds__(256) void oproj_kernel(
    const unsigned short* __restrict__ AW,
    const void* __restrict__ Wo,
    const int* __restrict__ flag,
    float* __restrict__ tmp)
{
  __shared__ __align__(16) unsigned short As[128 * LDA];
  __shared__ __align__(16) unsigned short Bs[128 * LDA];
  const int bf = *flag;
  const int t = threadIdx.x;
  const int lane = t & 63;
  const int w = t >> 6;
  const int wm = (w >> 1) * 64, wn = (w & 1) * 64;
  const int quad = lane >> 4, l16 = lane & 15;
  const int r0 = t >> 2, kc = (t & 3) * 8;
  const int r1 = r0 + 64;
  const int tm = blockIdx.y * 128, tn = blockIdx.x * 128;
  f32x4 acc[4][4];
#pragma unroll
  for (int mi = 0; mi < 4; ++mi)
#pragma unroll
    for (int ni = 0; ni < 4; ++ni)
      acc[mi][ni] = (f32x4){0.f, 0.f, 0.f, 0.f};

  for (int k0 = 0; k0 < D_MODEL; k0 += 32) {
    bf16x8 a0 = *(const bf16x8*)(AW + (size_t)(tm + r0) * D_MODEL + k0 + kc);
    bf16x8 a1 = *(const bf16x8*)(AW + (size_t)(tm + r1) * D_MODEL + k0 + kc);
    bf16x8 b0 = ld8(Wo, (size_t)(tn + r0) * D_MODEL + k0 + kc, bf);
    bf16x8 b1 = ld8(Wo, (size_t)(tn + r1) * D_MODEL + k0 + kc, bf);
    __syncthreads();
    *(bf16x8*)(As + r0 * LDA + kc) = a0;
    *(bf16x8*)(As + r1 * LDA + kc) = a1;
    *(bf16x8*)(Bs + r0 * LDA + kc) = b0;
    *(bf16x8*)(Bs + r1 * LDA + kc) = b1;
    __syncthreads();
    bf16x8 af[4], bfv[4];
#pragma unroll
    for (int mi = 0; mi < 4; ++mi)
      af[mi] = *(const bf16x8*)(As + (wm + mi * 16 + l16) * LDA + quad * 8);
#pragma unroll
    for (int ni = 0; ni < 4; ++ni)
      bfv[ni] = *(const bf16x8*)(Bs + (wn + ni * 16 + l16) * LDA + quad * 8);
#pragma unroll
    for (int mi = 0; mi < 4; ++mi)
#pragma unroll
      for (int ni = 0; ni < 4; ++ni)
        acc[mi][ni] = MFMA16(af[mi], bfv[ni], acc[mi][ni]);
  }
#pragma unroll
  for (int mi = 0; mi < 4; ++mi)
#pragma unroll
    for (int ni = 0; ni < 4; ++ni)
#pragma unroll
      for (int r = 0; r < 4; ++r) {
        int m = tm + wm + mi * 16 + quad * 4 + r;
        int n = tn + wn + ni * 16 + l16;
        tmp[(size_t)m * D_MODEL + n] = acc[mi][ni][r];
      }
}

// ======================= Flash attention (shared-KV paired tiles) =======
// 512 blocks x 256 thr (4 waves, 2 waves/SIMD). Block owns q-tiles
// tA=31-p and tB=p (causal; non-causal 2p/2p+1). B's kv range 0..p is a
// PREFIX of A's 0..31-p: iterate kv ONCE over A's range, compute both tiles
// per item while kv <= p. ITEMS = 32-p varies per block — R9: co-resident
// pair (bid, bid+256) differs by bhl+=2, so p_eff = (bhl&2)? 15-p : p gives
// the pair complementary p -> per-CU items (32-p)+(17+p) = 49 CONSTANT
// (fixes the straggler-CU tail R6 reintroduced: makespan was 64 vs mean 49).
// TRIPLE-BUFFERED depth-2 prefetch, counted vmcnt(4) + RAW s_barrier.
// K rows staged sigma-PERMUTED so S^T C-layout == PV B-operand layout; P is
// lane-local (cvt_pk pack), no LDS round-trip.
__device__ __forceinline__ void qk_part(
    const bf16x8 (&kfr)[4][2], const bf16x8 (&aq)[2], f32x4 (&sc)[4])
{
  __builtin_amdgcn_s_setprio(1);
#pragma unroll
  for (int cb = 0; cb < 4; ++cb) {
    sc[cb] = (f32x4){0.f, 0.f, 0.f, 0.f};
    sc[cb] = MFMA16(kfr[cb][0], aq[0], sc[cb]);
    sc[cb] = MFMA16(kfr[cb][1], aq[1], sc[cb]);
  }
  __builtin_amdgcn_s_setprio(0);
}

__device__ __forceinline__ void smpv_part(
    f32x4 (&sc)[4], const bf16x8 (&vfr)[4][2], f32x4 (&oacc)[4], float& lsum,
    int diag, int ktbase, int qq, int quad, float Cs)
{
  if (diag) {
#pragma unroll
    for (int cb = 0; cb < 4; ++cb)
#pragma unroll
      for (int rr = 0; rr < 4; ++rr)
        if (ktbase + (cb & 1) * 32 + quad * 8 + (cb >> 1) * 4 + rr > qq)
          sc[cb][rr] = NEG_BIG;
  }
  // no-max softmax: p = exp2(s*Cs); masked -> exp2(-huge) = 0
#pragma unroll
  for (int cb = 0; cb < 4; ++cb)
#pragma unroll
    for (int rr = 0; rr < 4; ++rr)
      sc[cb][rr] = __builtin_amdgcn_exp2f(sc[cb][rr] * Cs);
  // pairwise-tree row-sum (log depth)
  f32x4 t0, t1;
#pragma unroll
  for (int rr = 0; rr < 4; ++rr) { t0[rr] = sc[0][rr] + sc[1][rr]; }
#pragma unroll
  for (int rr = 0; rr < 4; ++rr) { t1[rr] = sc[2][rr] + sc[3][rr]; }
#pragma unroll
  for (int rr = 0; rr < 4; ++rr) { t0[rr] += t1[rr]; }
  lsum += (t0[0] + t0[1]) + (t0[2] + t0[3]);
  // lane-local pack: bp[hf] elems j=0..3 <- sc[hf], j=4..7 <- sc[2+hf]
  bf16x8 bp[2];
#pragma unroll
  for (int hf = 0; hf < 2; ++hf) {
    union { unsigned int w4[4]; bf16x8 v; } u;
    u.w4[0] = cvtpk_bf16(sc[hf][0], sc[hf][1]);
    u.w4[1] = cvtpk_bf16(sc[hf][2], sc[hf][3]);
    u.w4[2] = cvtpk_bf16(sc[2 + hf][0], sc[2 + hf][1]);
    u.w4[3] = cvtpk_bf16(sc[2 + hf][2], sc[2 + hf][3]);
    bp[hf] = u.v;
  }
  // O^T += V^T · P^T : C col = q, row = d
  __builtin_amdgcn_s_setprio(1);
#pragma unroll
  for (int db = 0; db < 4; ++db) {
    oacc[db] = MFMA16(vfr[db][0], bp[0], oacc[db]);
    oacc[db] = MFMA16(vfr[db][1], bp[1], oacc[db]);
  }
  __builtin_amdgcn_s_setprio(0);
}

__global__ __launch_bounds__(256, 2) void attn_kernel(
    unsigned short* __restrict__ Qd,   // Q in (plain [m,n]), attn-out in place
    const unsigned short* __restrict__ Kb,
    const unsigned short* __restrict__ Vt,
    const int* __restrict__ causal_p)
{
  __shared__ __align__(16) unsigned short Ks[3][64 * 64];
  __shared__ __align__(16) unsigned short Vs[3][64 * 64];
  const int bid = blockIdx.x;
  const int xcd = bid & 7, slot = bid >> 3;     // 512 blocks -> 64 slots/xcd
  const int bhl = slot >> 4;                    // 0..3
  const int praw = slot & 15;
  const int p = (bhl & 2) ? (15 - praw) : praw; // complementary-p pairing (R9)
  const int bh = xcd * 4 + bhl;
  const int b = bh >> 4, h = bh & 15;
  const int t = threadIdx.x, lane = t & 63, w = t >> 6;   // w in {0..3}
  const int quad = lane >> 4, l16 = lane & 15;
  const int causal = *causal_p;
  const int tA = causal ? (31 - p) : (2 * p);
  const int tB = causal ? p : (2 * p + 1);
  const int ITEMS = causal ? (32 - p) : 32;     // kv tiles for A (superset)
  unsigned short* qh = Qd + (size_t)b * SEQ * D_MODEL + h * HD;  // row stride D_MODEL
  const unsigned short* kh = Kb + ((size_t)b * NH + h) * SEQ * HD;
  const unsigned short* vh = Vt + ((size_t)b * NH + h) * HD * SEQ;
  const float Cs = 0.125f * 1.4426950408889634f;  // scale * log2(e)
  const int srow = lane >> 3;                     // staging: 8 rows / instr
  const int gcol = ((lane & 7) ^ srow) * 8;       // swizzled global chunk
  const int xa = l16 & 7;                         // read-side swizzle key

  // per-lane permuted K source rows for the two K staging instructions
  int kvp[2];
#pragma unroll
  for (int j2 = 0; j2 < 2; ++j2) {
    const int rp = w * 16 + j2 * 8 + srow;
    kvp[j2] = ((rp >> 4) & 1) * 32 + ((rp >> 2) & 3) * 8 + ((rp >> 5) & 1) * 4 + (rp & 3);
  }

  // Q fragments: wave w owns the 16-row strip tile*64 + w*16
  const int qA = tA * 64 + w * 16, qB = tB * 64 + w * 16;
  bf16x8 aqA[2], aqB[2];
#pragma unroll
  for (int ch = 0; ch < 2; ++ch) {
    aqA[ch] = *(const bf16x8*)(qh + (size_t)(qA + l16) * D_MODEL +
                               ch * 32 + quad * 8);
    aqB[ch] = *(const bf16x8*)(qh + (size_t)(qB + l16) * D_MODEL +
                               ch * 32 + quad * 8);
  }

  f32x4 oaccA[4], oaccB[4];
#pragma unroll
  for (int db = 0; db < 4; ++db) {
    oaccA[db] = (f32x4){0.f, 0.f, 0.f, 0.f};
    oaccB[db] = (f32x4){0.f, 0.f, 0.f, 0.f};
  }
  float lsumA = 0.f, lsumB = 0.f;

  // staging: 4 async16 per thread per item (2 K permuted + 2 V natural);
  // 4 waves cover all 64 LDS rows of each tile. kv tile index == item f.
  auto stage = [&](int f, int buf) {
#pragma unroll
    for (int j2 = 0; j2 < 2; ++j2) {
      const int row = w * 16 + j2 * 8;
      async16(kh + (size_t)(f * 64 + kvp[j2]) * HD + gcol, &Ks[buf][row * 64]);
      async16(vh + (size_t)(row + srow) * SEQ + f * 64 + gcol, &Vs[buf][row * 64]);
    }
  };

  // prologue: Q loads above (4 vmcnt), then batches 0,1 (4 each)
  stage(0, 0);
  if (ITEMS > 1) stage(1, 1);

  int cur = 0, nb = 2;
  for (int f = 0; f < ITEMS; ++f) {
    // wait: batch f landed (own loads); newest batch may stay in flight
    if (f + 1 < ITEMS) asm volatile("s_waitcnt vmcnt(4)" ::: "memory");
    else               asm volatile("s_waitcnt vmcnt(0)" ::: "memory");
    __builtin_amdgcn_s_barrier();            // raw: no forced vmcnt(0) drain
    __builtin_amdgcn_sched_barrier(0);       // pin LDS reads behind barrier
    if (f + 2 < ITEMS) stage(f + 2, nb);

    // shared K/V fragments (read once, used by both tiles)
    bf16x8 kfr[4][2], vfr[4][2];
#pragma unroll
    for (int cb = 0; cb < 4; ++cb)
#pragma unroll
      for (int hf = 0; hf < 2; ++hf) {
        kfr[cb][hf] = *(const bf16x8*)(&Ks[cur][(cb * 16 + l16) * 64 +
                                               ((hf * 4 + quad) ^ xa) * 8]);
        vfr[cb][hf] = *(const bf16x8*)(&Vs[cur][(cb * 16 + l16) * 64 +
                                               ((hf * 4 + quad) ^ xa) * 8]);
      }
    const int bAct = causal ? (f <= p) : 1;
    f32x4 scA[4], scB[4];
    qk_part(kfr, aqA, scA);
    if (bAct) qk_part(kfr, aqB, scB);       // B's MFMAs drain under A's softmax
    smpv_part(scA, vfr, oaccA, lsumA,
              causal && (f == ITEMS - 1), f * 64, qA + l16, quad, Cs);
    if (bAct)
      smpv_part(scB, vfr, oaccB, lsumB,
                causal && (f == p), f * 64, qB + l16, quad, Cs);
    cur = (cur == 2) ? 0 : cur + 1;
    nb = (nb == 2) ? 0 : nb + 1;
  }

  // epilogue per tile: reduce lsum over quads, write packed bf16 in place
  {
    float l = lsumA;
    l += __shfl_xor(l, 16, 64);
    l += __shfl_xor(l, 32, 64);
    float inv = 1.0f / l;
#pragma unroll
    for (int db = 0; db < 4; ++db) {
      u16x4 o;
#pragma unroll
      for (int rr = 0; rr < 4; ++rr) o[rr] = f2bf(oaccA[db][rr] * inv);
      *(u16x4*)(qh + (size_t)(qA + l16) * D_MODEL + db * 16 + quad * 4) = o;
    }
  }
  {
    float l = lsumB;
    l += __shfl_xor(l, 16, 64);
    l += __shfl_xor(l, 32, 64);
    float inv = 1.0f / l;
#pragma unroll
    for (int db = 0; db < 4; ++db) {
      u16x4 o;
#pragma unroll
      for (int rr = 0; rr < 4; ++rr) o[rr] = f2bf(oaccB[db][rr] * inv);
      *(u16x4*)(qh + (size_t)(qB + l16) * D_MODEL + db * 16 + quad * 4) = o;
    }
  }
}

// ---- final: d_out <- tmp, dtype per detected flag (SLOW PATH ONLY) ----
__global__ __launch_bounds__(256) void final_kernel(
    const float* __restrict__ tmp, void* __restrict__ out,
    const int* __restrict__ flag)
{
  const int bf = *flag;
  size_t i = ((size_t)blockIdx.x * 256 + threadIdx.x) * 8;
  f32x4 lo = *(const f32x4*)(tmp + i);
  f32x4 hi = *(const f32x4*)(tmp + i + 4);
  if (bf) {
    bf16x8 r;
    r[0] = (short)f2bf(lo[0]); r[1] = (short)f2bf(lo[1]);
    r[2] = (short)f2bf(lo[2]); r[3] = (short)f2bf(lo[3]);
    r[4] = (short)f2bf(hi[0]); r[5] = (short)f2bf(hi[1]);
    r[6] = (short)f2bf(hi[2]); r[7] = (short)f2bf(hi[3]);
    *(bf16x8*)((unsigned short*)out + i) = r;
  } else {
    *(f32x4*)((float*)out + i) = lo;
    *(f32x4*)((float*)out + i + 4) = hi;
  }
}

extern "C" void kernel_launch(void* const* d_in, const int* in_sizes, int n_in,
                              void* d_out, int out_size, void* d_ws, size_t ws_size,
                              hipStream_t stream) {
  const void* X  = d_in[0];
  const void* Wq = d_in[1];
  const void* Wk = d_in[2];
  const void* Wv = d_in[3];
  const void* Wo = d_in[4];
  const int* causal = (const int*)d_in[5];

  const size_t NE = (size_t)2 * SEQ * D_MODEL;   // 4,194,304 elems
  const size_t WE = (size_t)D_MODEL * D_MODEL;   // 1,048,576 elems
  int* flag0 = (int*)d_ws;

  // fast path layout (all in ws; d_out untouched until oproj writes it):
  //   [64B flag][kws 8M][vws 8M][Wb 8M][qd 8M][Xb 8M]  = 40 MB + 64
  unsigned short* kws = (unsigned short*)((char*)d_ws + 64);
  unsigned short* vws = kws + NE;
  unsigned short* Wb  = vws + NE;
  unsigned short* qdf = Wb + 4 * WE;             // fast-path Q/attn buffer
  unsigned short* Xbf = qdf + NE;                // fast-path X bf16

  const bool big = ws_size >= (size_t)64 + 40ull * 1024 * 1024;

  if (big) {
    // fast path: 4 kernels, dtype detected inline where needed
    hipLaunchKernelGGL(convert_kernel, dim3(2048, 5), dim3(256), 0, stream,
                       X, Wq, Wk, Wv, Wo, Xbf, Wb);
    hipLaunchKernelGGL(qkv_fast_kernel, dim3(768), dim3(256), 0, stream,
                       Xbf, Wb, qdf, kws, vws);
    hipLaunchKernelGGL(attn_kernel, dim3(512), dim3(256), 0, stream,
                       qdf, kws, vws, causal);
    hipLaunchKernelGGL(oproj_fast_kernel, dim3(512), dim3(256), 0, stream,
                       qdf, Wb + 3 * WE, (const unsigned short*)X, d_out);
  } else {
    // slow path: legacy layout (qd aliases d_out; tmp over dead K/V)
    float* tmp = (float*)kws;
    unsigned short* qd = (unsigned short*)d_out;
    hipLaunchKernelGGL(detect_kernel, dim3(1), dim3(64), 0, stream,
                       (const unsigned short*)X, flag0);
    hipLaunchKernelGGL(qkv_kernel, dim3(8, 32, 3), dim3(256), 0, stream,
                       X, Wq, Wk, Wv, flag0, qd, kws, vws);
    hipLaunchKernelGGL(attn_kernel, dim3(512), dim3(256), 0, stream,
                       qd, kws, vws, causal);
    hipLaunchKernelGGL(oproj_kernel, dim3(8, 32), dim3(256), 0, stream,
                       qd, Wo, flag0, tmp);
    hipLaunchKernelGGL(final_kernel, dim3(2048), dim3(256), 0, stream,
                       tmp, d_out, flag0);
  }
}

// Round 10
// 171.809 us; speedup vs baseline: 1.0584x; 1.0020x over previous
//
#include <hip/hip_runtime.h>

typedef __attribute__((ext_vector_type(8))) short bf16x8;
typedef __attribute__((ext_vector_type(4))) float f32x4;
typedef __attribute__((ext_vector_type(4))) unsigned short u16x4;

#define MFMA16(a, b, c) __builtin_amdgcn_mfma_f32_16x16x32_bf16((a), (b), (c), 0, 0, 0)

static constexpr int D_MODEL = 1024;
static constexpr int SEQ = 2048;
static constexpr int NH = 16;
static constexpr int HD = 64;
static constexpr int LDA = 40;   // slow-path GEMM LDS row stride
static constexpr int MST = 136;  // V^T repack LDS row stride (elems)
static constexpr float NEG_BIG = -1.0e30f;

__device__ __forceinline__ unsigned short f2bf(float f) {
  union { float f; unsigned int u; } v; v.f = f;
  unsigned int r = v.u + 0x7fffu + ((v.u >> 16) & 1u);
  return (unsigned short)(r >> 16);
}

// packed f32x2 -> bf16x2 (RNE), one VALU op
__device__ __forceinline__ unsigned int cvtpk_bf16(float a, float b) {
  unsigned int r;
  asm("v_cvt_pk_bf16_f32 %0, %1, %2" : "=v"(r) : "v"(a), "v"(b));
  return r;
}

// Inline dtype scan (identical logic to detect_kernel): every wave reads the
// same 64 even-index u16 of X and votes; result is wave-uniform. ~128B, L2-hot.
__device__ __forceinline__ int detect_bf16(const unsigned short* xs, int lane) {
  unsigned short s = xs[2 * lane];
  int e = (s >> 7) & 0xFF;
  bool hit = (e >= 117 && e <= 129);
  unsigned long long m = __ballot(hit);
  return (__popcll(m) >= 32) ? 1 : 0;
}

// Adaptive 8-element load: bf16 direct, or f32 -> RNE bf16 convert (slow path).
__device__ __forceinline__ bf16x8 ld8(const void* p, size_t eidx, int bf) {
  if (bf) return *(const bf16x8*)((const unsigned short*)p + eidx);
  const float* f = (const float*)p + eidx;
  f32x4 lo = *(const f32x4*)f;
  f32x4 hi = *(const f32x4*)(f + 4);
  bf16x8 r;
  r[0] = (short)f2bf(lo[0]); r[1] = (short)f2bf(lo[1]);
  r[2] = (short)f2bf(lo[2]); r[3] = (short)f2bf(lo[3]);
  r[4] = (short)f2bf(hi[0]); r[5] = (short)f2bf(hi[1]);
  r[6] = (short)f2bf(hi[2]); r[7] = (short)f2bf(hi[3]);
  return r;
}

// async global -> LDS, 16B per lane (dst = wave-uniform base + lane*16)
__device__ __forceinline__ void async16(const unsigned short* g, unsigned short* l) {
  __builtin_amdgcn_global_load_lds(
      (const __attribute__((address_space(1))) void*)g,
      (__attribute__((address_space(3))) void*)l, 16, 0, 0);
}

// ---- dtype detector (SLOW PATH ONLY; fast path inlines the scan) ----
__global__ __launch_bounds__(64) void detect_kernel(
    const unsigned short* __restrict__ xs, int* __restrict__ flag) {
  int lane = threadIdx.x;
  unsigned short s = xs[2 * lane];
  int e = (s >> 7) & 0xFF;
  bool hit = (e >= 117 && e <= 129);
  unsigned long long m = __ballot(hit);
  if (lane == 0) { flag[0] = (__popcll(m) >= 32) ? 1 : 0; flag[1] = 1; }
}

// ---- pre-convert X and the four W matrices to bf16 (fast path) ----
__global__ __launch_bounds__(256) void convert_kernel(
    const void* __restrict__ X,
    const void* __restrict__ W0, const void* __restrict__ W1,
    const void* __restrict__ W2, const void* __restrict__ W3,
    unsigned short* __restrict__ Xb, unsigned short* __restrict__ Wb)
{
  const int bf = detect_bf16((const unsigned short*)X, threadIdx.x & 63);
  const int ty = blockIdx.y;
  const void* src; unsigned short* dst; size_t n;
  if (ty == 0) { src = X; dst = Xb; n = (size_t)2 * SEQ * D_MODEL; }
  else {
    src = (ty == 1) ? W0 : (ty == 2) ? W1 : (ty == 3) ? W2 : W3;
    dst = Wb + (size_t)(ty - 1) * D_MODEL * D_MODEL;
    n = (size_t)D_MODEL * D_MODEL;
  }
  size_t i = ((size_t)blockIdx.x * 256 + threadIdx.x) * 8;
  if (i >= n) return;
  *(bf16x8*)(dst + i) = ld8(src, i, bf);
}

// ======================= FAST PATH bf16 GEMM =======================
// 128x128 tile, BK=32, TRIPLE-BUFFERED depth-2 prefetch (attn-validated
// schedule): stage item f+2 each iter; counted vmcnt(4) wait + raw s_barrier
// -> each stage gets ~2 compute phases to land. 48 KB LDS -> 3 blocks/CU.
// Swizzle (32-elem rows): LDS[r][c] = G[r][c ^ ((r>>1)&3)].
__device__ __forceinline__ void gemm_fast_core(
    const unsigned short* __restrict__ A, const unsigned short* __restrict__ B,
    int tm, int tn, unsigned short* smem, f32x4 acc[4][4])
{
  const int t = threadIdx.x;
  const int lane = t & 63;
  const int w = t >> 6;
  const int wm = (w >> 1) * 64, wn = (w & 1) * 64;
  const int quad = lane >> 4, l16 = lane & 15;
  const int srow = lane >> 2;                          // 16 rows per async16
  const int scol = ((lane & 3) ^ ((lane >> 3) & 3)) * 8;  // swizzled src chunk
  const int xa = (l16 >> 1) & 3;                       // read-side swizzle key

#pragma unroll
  for (int mi = 0; mi < 4; ++mi)
#pragma unroll
    for (int ni = 0; ni < 4; ++ni)
      acc[mi][ni] = (f32x4){0.f, 0.f, 0.f, 0.f};

  // stage K-tile f (32 wide) into buffer buf: 4 async16 per thread
  auto stage = [&](int f, int buf) {
    const int k0 = f * 32;
    unsigned short* dst = smem + buf * 8192;
#pragma unroll
    for (int i = 0; i < 2; ++i) {
      const int row = w * 32 + i * 16;
      async16(A + (size_t)(tm + row + srow) * D_MODEL + k0 + scol,
              dst + row * 32);
      async16(B + (size_t)(tn + row + srow) * D_MODEL + k0 + scol,
              dst + 4096 + row * 32);
    }
  };

  stage(0, 0);
  stage(1, 1);

  int cur = 0, nb = 2;
  for (int f = 0; f < 32; ++f) {
    if (f + 1 < 32) asm volatile("s_waitcnt vmcnt(4)" ::: "memory");
    else            asm volatile("s_waitcnt vmcnt(0)" ::: "memory");
    __builtin_amdgcn_s_barrier();            // raw: no forced vmcnt(0) drain
    __builtin_amdgcn_sched_barrier(0);       // pin LDS reads behind barrier
    if (f + 2 < 32) stage(f + 2, nb);
    const unsigned short* As = smem + cur * 8192;
    const unsigned short* Bs = As + 4096;
    bf16x8 af[4], bfv[4];
#pragma unroll
    for (int mi = 0; mi < 4; ++mi)
      af[mi] = *(const bf16x8*)(As + (wm + mi * 16 + l16) * 32 + (quad ^ xa) * 8);
#pragma unroll
    for (int ni = 0; ni < 4; ++ni)
      bfv[ni] = *(const bf16x8*)(Bs + (wn + ni * 16 + l16) * 32 + (quad ^ xa) * 8);
    __builtin_amdgcn_s_setprio(1);
#pragma unroll
    for (int mi = 0; mi < 4; ++mi)
#pragma unroll
      for (int ni = 0; ni < 4; ++ni)
        acc[mi][ni] = MFMA16(af[mi], bfv[ni], acc[mi][ni]);
    __builtin_amdgcn_s_setprio(0);
    cur = (cur == 2) ? 0 : cur + 1;
    nb = (nb == 2) ? 0 : nb + 1;
  }
}

// QKV fast: 1D grid 768. XCD partition: xcd (bid&7) owns M-chunk xcd*512
// (X panels XCD-local). s0 order: z slowest, tn mid, tm_local fastest.
__global__ __launch_bounds__(256) void qkv_fast_kernel(
    const unsigned short* __restrict__ X,
    const unsigned short* __restrict__ Wb,   // [3][1024][1024] bf16 (q,k,v)
    unsigned short* __restrict__ qd,
    unsigned short* __restrict__ kws,
    unsigned short* __restrict__ vws)
{
  __shared__ __align__(16) unsigned short smem[3 * 8192];  // 48 KB triple-buf
  const int bid = blockIdx.x;
  const int xcd = bid & 7, s0 = bid >> 3;      // s0 in 0..95
  const int z = s0 >> 5;                       // 0..2
  const int tn = ((s0 >> 2) & 7) * 128;
  const int tm = (xcd * 4 + (s0 & 3)) * 128;
  const unsigned short* W = Wb + (size_t)z * D_MODEL * D_MODEL;
  f32x4 acc[4][4];
  gemm_fast_core(X, W, tm, tn, smem, acc);

  const int t = threadIdx.x;
  const int lane = t & 63, w = t >> 6;
  const int wm = (w >> 1) * 64, wn = (w & 1) * 64;
  const int quad = lane >> 4, l16 = lane & 15;

  if (z == 2) {
    // V^T epilogue: LDS transpose repack (2 n-half passes) + coalesced stores.
    const int b = tm >> 11;
    const int sb = tm & 2047;
#pragma unroll
    for (int ph = 0; ph < 2; ++ph) {
      __syncthreads();
      if ((w & 1) == ph) {
#pragma unroll
        for (int mi = 0; mi < 4; ++mi)
#pragma unroll
          for (int ni = 0; ni < 4; ++ni)
#pragma unroll
            for (int r = 0; r < 4; ++r) {
              int m_local = wm + mi * 16 + quad * 4 + r;
              int n_sub = ni * 16 + l16;
              smem[n_sub * MST + m_local] = f2bf(acc[mi][ni][r]);
            }
      }
      __syncthreads();
      const int row = t >> 2, c0 = (t & 3) * 32;
      const int n_g = tn + ph * 64 + row;
      const int h = n_g >> 6, d = n_g & 63;
      unsigned short* dst = vws + (((size_t)b * NH + h) * HD + d) * SEQ + sb + c0;
#pragma unroll
      for (int cc = 0; cc < 4; ++cc)
        *(bf16x8*)(dst + cc * 8) = *(const bf16x8*)(smem + row * MST + c0 + cc * 8);
    }
    return;
  }
#pragma unroll
  for (int mi = 0; mi < 4; ++mi)
#pragma unroll
    for (int ni = 0; ni < 4; ++ni)
#pragma unroll
      for (int r = 0; r < 4; ++r) {
        int m = tm + wm + mi * 16 + quad * 4 + r;
        int n = tn + wn + ni * 16 + l16;
        unsigned short bv = f2bf(acc[mi][ni][r]);
        if (z == 0) {
          qd[(size_t)m * D_MODEL + n] = bv;
        } else {
          int b = m >> 11, sg = m & 2047;
          int h = n >> 6, d = n & 63;
          kws[(((size_t)b * NH + h) * SEQ + sg) * HD + d] = bv;
        }
      }
}

// O-proj fast: R10 — REVERT to 256 blocks x 128x128 (R6 geometry; the R7
// 512x(128x64) rework regressed ~12us: same per-K-step stall skeleton with
// half the MFMA payload). Keeps R8 direct-d_out dtype-branched write.
__global__ __launch_bounds__(256) void oproj_fast_kernel(
    const unsigned short* __restrict__ AW,
    const unsigned short* __restrict__ Wo,
    const unsigned short* __restrict__ Xorig,   // for inline dtype detect
    void* __restrict__ out)
{
  __shared__ __align__(16) unsigned short smem[3 * 8192];  // 48 KB triple-buf
  const int bf = detect_bf16(Xorig, threadIdx.x & 63);
  const int bid = blockIdx.x;
  const int xcd = bid & 7, s0 = bid >> 3;      // s0 in 0..31
  const int tmg = xcd >> 2, tng = xcd & 3;
  const int tm = (tmg * 16 + (s0 >> 1)) * 128;
  const int tn = (tng * 2 + (s0 & 1)) * 128;
  f32x4 acc[4][4];
  gemm_fast_core(AW, Wo, tm, tn, smem, acc);

  const int t = threadIdx.x;
  const int lane = t & 63, w = t >> 6;
  const int wm = (w >> 1) * 64, wn = (w & 1) * 64;
  const int quad = lane >> 4, l16 = lane & 15;
  if (bf) {
    unsigned short* o = (unsigned short*)out;
#pragma unroll
    for (int mi = 0; mi < 4; ++mi)
#pragma unroll
      for (int ni = 0; ni < 4; ++ni)
#pragma unroll
        for (int r = 0; r < 4; ++r) {
          int m = tm + wm + mi * 16 + quad * 4 + r;
          int n = tn + wn + ni * 16 + l16;
          o[(size_t)m * D_MODEL + n] = f2bf(acc[mi][ni][r]);
        }
  } else {
    float* o = (float*)out;
#pragma unroll
    for (int mi = 0; mi < 4; ++mi)
#pragma unroll
      for (int ni = 0; ni < 4; ++ni)
#pragma unroll
        for (int r = 0; r < 4; ++r) {
          int m = tm + wm + mi * 16 + quad * 4 + r;
          int n = tn + wn + ni * 16 + l16;
          o[(size_t)m * D_MODEL + n] = acc[mi][ni][r];
        }
  }
}

// ======================= SLOW PATH GEMM (dtype-adaptive) =======================
__device__ __forceinline__ void gemm_tile_128x128(
    const void* __restrict__ A, const void* __restrict__ B, int bf,
    int tm, int tn, unsigned short* As, unsigned short* Bs, f32x4 acc[4][4])
{
  const int t = threadIdx.x;
  const int lane = t & 63;
  const int w = t >> 6;
  const int wm = (w >> 1) * 64, wn = (w & 1) * 64;
  const int quad = lane >> 4, l16 = lane & 15;
  const int r0 = t >> 2, kc = (t & 3) * 8;
  const int r1 = r0 + 64;

#pragma unroll
  for (int mi = 0; mi < 4; ++mi)
#pragma unroll
    for (int ni = 0; ni < 4; ++ni)
      acc[mi][ni] = (f32x4){0.f, 0.f, 0.f, 0.f};

  for (int k0 = 0; k0 < D_MODEL; k0 += 32) {
    bf16x8 a0 = ld8(A, (size_t)(tm + r0) * D_MODEL + k0 + kc, bf);
    bf16x8 a1 = ld8(A, (size_t)(tm + r1) * D_MODEL + k0 + kc, bf);
    bf16x8 b0 = ld8(B, (size_t)(tn + r0) * D_MODEL + k0 + kc, bf);
    bf16x8 b1 = ld8(B, (size_t)(tn + r1) * D_MODEL + k0 + kc, bf);
    __syncthreads();
    *(bf16x8*)(As + r0 * LDA + kc) = a0;
    *(bf16x8*)(As + r1 * LDA + kc) = a1;
    *(bf16x8*)(Bs + r0 * LDA + kc) = b0;
    *(bf16x8*)(Bs + r1 * LDA + kc) = b1;
    __syncthreads();
    bf16x8 af[4], bfv[4];
#pragma unroll
    for (int mi = 0; mi < 4; ++mi)
      af[mi] = *(const bf16x8*)(As + (wm + mi * 16 + l16) * LDA + quad * 8);
#pragma unroll
    for (int ni = 0; ni < 4; ++ni)
      bfv[ni] = *(const bf16x8*)(Bs + (wn + ni * 16 + l16) * LDA + quad * 8);
#pragma unroll
    for (int mi = 0; mi < 4; ++mi)
#pragma unroll
      for (int ni = 0; ni < 4; ++ni)
        acc[mi][ni] = MFMA16(af[mi], bfv[ni], acc[mi][ni]);
  }
}

__global__ __launch_bounds__(256) void qkv_kernel(
    const void* __restrict__ X,
    const void* __restrict__ Wq,
    const void* __restrict__ Wk,
    const void* __restrict__ Wv,
    const int* __restrict__ flag,
    unsigned short* __restrict__ qd,
    unsigned short* __restrict__ kws,
    unsigned short* __restrict__ vws)
{
  __shared__ __align__(16) unsigned short As[128 * LDA];
  __shared__ __align__(16) unsigned short Bs[128 * LDA];
  const int bf = *flag;
  const int z = blockIdx.z;
  const void* W = (z == 0) ? Wq : ((z == 1) ? Wk : Wv);
  const int tm = blockIdx.y * 128, tn = blockIdx.x * 128;
  f32x4 acc[4][4];
  gemm_tile_128x128(X, W, bf, tm, tn, As, Bs, acc);

  const int t = threadIdx.x;
  const int lane = t & 63, w = t >> 6;
  const int wm = (w >> 1) * 64, wn = (w & 1) * 64;
  const int quad = lane >> 4, l16 = lane & 15;
#pragma unroll
  for (int mi = 0; mi < 4; ++mi)
#pragma unroll
    for (int ni = 0; ni < 4; ++ni)
#pragma unroll
      for (int r = 0; r < 4; ++r) {
        int m = tm + wm + mi * 16 + quad * 4 + r;
        int n = tn + wn + ni * 16 + l16;
        unsigned short bv = f2bf(acc[mi][ni][r]);
        if (z == 0) {
          qd[(size_t)m * D_MODEL + n] = bv;
        } else {
          int b = m >> 11, s = m & 2047;
          int h = n >> 6, d = n & 63;
          if (z == 1) kws[(((size_t)b * NH + h) * SEQ + s) * HD + d] = bv;
          else        vws[(((size_t)b * NH + h) * HD + d) * SEQ + s] = bv;
        }
      }
}

__global__ __launch_bounds__(256) void oproj_kernel(
    const unsigned short* __restrict__ AW,
    const void* __restrict__ Wo,
    const int* __restrict__ flag,
    float* __restrict__ tmp)
{
  __shared__ __align__(16) unsigned short As[128 * LDA];
  __shared__ __align__(16) unsigned short Bs[128 * LDA];
  const int bf = *flag;
  const int t = threadIdx.x;
  const int lane = t & 63;
  const int w = t >> 6;
  const int wm = (w >> 1) * 64, wn = (w & 1) * 64;
  const int quad = lane >> 4, l16 = lane & 15;
  const int r0 = t >> 2, kc = (t & 3) * 8;
  const int r1 = r0 + 64;
  const int tm = blockIdx.y * 128, tn = blockIdx.x * 128;
  f32x4 acc[4][4];
#pragma unroll
  for (int mi = 0; mi < 4; ++mi)
#pragma unroll
    for (int ni = 0; ni < 4; ++ni)
      acc[mi][ni] = (f32x4){0.f, 0.f, 0.f, 0.f};

  for (int k0 = 0; k0 < D_MODEL; k0 += 32) {
    bf16x8 a0 = *(const bf16x8*)(AW + (size_t)(tm + r0) * D_MODEL + k0 + kc);
    bf16x8 a1 = *(const bf16x8*)(AW + (size_t)(tm + r1) * D_MODEL + k0 + kc);
    bf16x8 b0 = ld8(Wo, (size_t)(tn + r0) * D_MODEL + k0 + kc, bf);
    bf16x8 b1 = ld8(Wo, (size_t)(tn + r1) * D_MODEL + k0 + kc, bf);
    __syncthreads();
    *(bf16x8*)(As + r0 * LDA + kc) = a0;
    *(bf16x8*)(As + r1 * LDA + kc) = a1;
    *(bf16x8*)(Bs + r0 * LDA + kc) = b0;
    *(bf16x8*)(Bs + r1 * LDA + kc) = b1;
    __syncthreads();
    bf16x8 af[4], bfv[4];
#pragma unroll
    for (int mi = 0; mi < 4; ++mi)
      af[mi] = *(const bf16x8*)(As + (wm + mi * 16 + l16) * LDA + quad * 8);
#pragma unroll
    for (int ni = 0; ni < 4; ++ni)
      bfv[ni] = *(const bf16x8*)(Bs + (wn + ni * 16 + l16) * LDA + quad * 8);
#pragma unroll
    for (int mi = 0; mi < 4; ++mi)
#pragma unroll
      for (int ni = 0; ni < 4; ++ni)
        acc[mi][ni] = MFMA16(af[mi], bfv[ni], acc[mi][ni]);
  }
#pragma unroll
  for (int mi = 0; mi < 4; ++mi)
#pragma unroll
    for (int ni = 0; ni < 4; ++ni)
#pragma unroll
      for (int r = 0; r < 4; ++r) {
        int m = tm + wm + mi * 16 + quad * 4 + r;
        int n = tn + wn + ni * 16 + l16;
        tmp[(size_t)m * D_MODEL + n] = acc[mi][ni][r];
      }
}

// ======================= Flash attention (shared-KV paired tiles) =======
// 512 blocks x 256 thr (4 waves, 2 waves/SIMD). Block owns q-tiles
// tA=31-p and tB=p (causal; non-causal 2p/2p+1). B's kv range 0..p is a
// PREFIX of A's 0..31-p: iterate kv ONCE over A's range, compute both tiles
// per item while kv <= p. Complementary-p pairing keeps per-CU items ~49.
// TRIPLE-BUFFERED depth-2 prefetch, counted vmcnt(4) + RAW s_barrier.
// K rows staged sigma-PERMUTED so S^T C-layout == PV B-operand layout; P is
// lane-local (cvt_pk pack), no LDS round-trip.
__device__ __forceinline__ void qk_part(
    const bf16x8 (&kfr)[4][2], const bf16x8 (&aq)[2], f32x4 (&sc)[4])
{
  __builtin_amdgcn_s_setprio(1);
#pragma unroll
  for (int cb = 0; cb < 4; ++cb) {
    sc[cb] = (f32x4){0.f, 0.f, 0.f, 0.f};
    sc[cb] = MFMA16(kfr[cb][0], aq[0], sc[cb]);
    sc[cb] = MFMA16(kfr[cb][1], aq[1], sc[cb]);
  }
  __builtin_amdgcn_s_setprio(0);
}

__device__ __forceinline__ void smpv_part(
    f32x4 (&sc)[4], const bf16x8 (&vfr)[4][2], f32x4 (&oacc)[4], float& lsum,
    int diag, int ktbase, int qq, int quad, float Cs)
{
  if (diag) {
#pragma unroll
    for (int cb = 0; cb < 4; ++cb)
#pragma unroll
      for (int rr = 0; rr < 4; ++rr)
        if (ktbase + (cb & 1) * 32 + quad * 8 + (cb >> 1) * 4 + rr > qq)
          sc[cb][rr] = NEG_BIG;
  }
  // no-max softmax: p = exp2(s*Cs); masked -> exp2(-huge) = 0
#pragma unroll
  for (int cb = 0; cb < 4; ++cb)
#pragma unroll
    for (int rr = 0; rr < 4; ++rr)
      sc[cb][rr] = __builtin_amdgcn_exp2f(sc[cb][rr] * Cs);
  // pairwise-tree row-sum (log depth)
  f32x4 t0, t1;
#pragma unroll
  for (int rr = 0; rr < 4; ++rr) { t0[rr] = sc[0][rr] + sc[1][rr]; }
#pragma unroll
  for (int rr = 0; rr < 4; ++rr) { t1[rr] = sc[2][rr] + sc[3][rr]; }
#pragma unroll
  for (int rr = 0; rr < 4; ++rr) { t0[rr] += t1[rr]; }
  lsum += (t0[0] + t0[1]) + (t0[2] + t0[3]);
  // lane-local pack: bp[hf] elems j=0..3 <- sc[hf], j=4..7 <- sc[2+hf]
  bf16x8 bp[2];
#pragma unroll
  for (int hf = 0; hf < 2; ++hf) {
    union { unsigned int w4[4]; bf16x8 v; } u;
    u.w4[0] = cvtpk_bf16(sc[hf][0], sc[hf][1]);
    u.w4[1] = cvtpk_bf16(sc[hf][2], sc[hf][3]);
    u.w4[2] = cvtpk_bf16(sc[2 + hf][0], sc[2 + hf][1]);
    u.w4[3] = cvtpk_bf16(sc[2 + hf][2], sc[2 + hf][3]);
    bp[hf] = u.v;
  }
  // O^T += V^T · P^T : C col = q, row = d
  __builtin_amdgcn_s_setprio(1);
#pragma unroll
  for (int db = 0; db < 4; ++db) {
    oacc[db] = MFMA16(vfr[db][0], bp[0], oacc[db]);
    oacc[db] = MFMA16(vfr[db][1], bp[1], oacc[db]);
  }
  __builtin_amdgcn_s_setprio(0);
}

__global__ __launch_bounds__(256, 2) void attn_kernel(
    unsigned short* __restrict__ Qd,   // Q in (plain [m,n]), attn-out in place
    const unsigned short* __restrict__ Kb,
    const unsigned short* __restrict__ Vt,
    const int* __restrict__ causal_p)
{
  __shared__ __align__(16) unsigned short Ks[3][64 * 64];
  __shared__ __align__(16) unsigned short Vs[3][64 * 64];
  const int bid = blockIdx.x;
  const int xcd = bid & 7, slot = bid >> 3;     // 512 blocks -> 64 slots/xcd
  const int bhl = slot >> 4;                    // 0..3
  const int praw = slot & 15;
  const int p = (bhl & 2) ? (15 - praw) : praw; // complementary-p pairing
  const int bh = xcd * 4 + bhl;
  const int b = bh >> 4, h = bh & 15;
  const int t = threadIdx.x, lane = t & 63, w = t >> 6;   // w in {0..3}
  const int quad = lane >> 4, l16 = lane & 15;
  const int causal = *causal_p;
  const int tA = causal ? (31 - p) : (2 * p);
  const int tB = causal ? p : (2 * p + 1);
  const int ITEMS = causal ? (32 - p) : 32;     // kv tiles for A (superset)
  unsigned short* qh = Qd + (size_t)b * SEQ * D_MODEL + h * HD;  // row stride D_MODEL
  const unsigned short* kh = Kb + ((size_t)b * NH + h) * SEQ * HD;
  const unsigned short* vh = Vt + ((size_t)b * NH + h) * HD * SEQ;
  const float Cs = 0.125f * 1.4426950408889634f;  // scale * log2(e)
  const int srow = lane >> 3;                     // staging: 8 rows / instr
  const int gcol = ((lane & 7) ^ srow) * 8;       // swizzled global chunk
  const int xa = l16 & 7;                         // read-side swizzle key

  // per-lane permuted K source rows for the two K staging instructions
  int kvp[2];
#pragma unroll
  for (int j2 = 0; j2 < 2; ++j2) {
    const int rp = w * 16 + j2 * 8 + srow;
    kvp[j2] = ((rp >> 4) & 1) * 32 + ((rp >> 2) & 3) * 8 + ((rp >> 5) & 1) * 4 + (rp & 3);
  }

  // Q fragments: wave w owns the 16-row strip tile*64 + w*16
  const int qA = tA * 64 + w * 16, qB = tB * 64 + w * 16;
  bf16x8 aqA[2], aqB[2];
#pragma unroll
  for (int ch = 0; ch < 2; ++ch) {
    aqA[ch] = *(const bf16x8*)(qh + (size_t)(qA + l16) * D_MODEL +
                               ch * 32 + quad * 8);
    aqB[ch] = *(const bf16x8*)(qh + (size_t)(qB + l16) * D_MODEL +
                               ch * 32 + quad * 8);
  }

  f32x4 oaccA[4], oaccB[4];
#pragma unroll
  for (int db = 0; db < 4; ++db) {
    oaccA[db] = (f32x4){0.f, 0.f, 0.f, 0.f};
    oaccB[db] = (f32x4){0.f, 0.f, 0.f, 0.f};
  }
  float lsumA = 0.f, lsumB = 0.f;

  // staging: 4 async16 per thread per item (2 K permuted + 2 V natural);
  // 4 waves cover all 64 LDS rows of each tile. kv tile index == item f.
  auto stage = [&](int f, int buf) {
#pragma unroll
    for (int j2 = 0; j2 < 2; ++j2) {
      const int row = w * 16 + j2 * 8;
      async16(kh + (size_t)(f * 64 + kvp[j2]) * HD + gcol, &Ks[buf][row * 64]);
      async16(vh + (size_t)(row + srow) * SEQ + f * 64 + gcol, &Vs[buf][row * 64]);
    }
  };

  // prologue: Q loads above (4 vmcnt), then batches 0,1 (4 each)
  stage(0, 0);
  if (ITEMS > 1) stage(1, 1);

  int cur = 0, nb = 2;
  for (int f = 0; f < ITEMS; ++f) {
    // wait: batch f landed (own loads); newest batch may stay in flight
    if (f + 1 < ITEMS) asm volatile("s_waitcnt vmcnt(4)" ::: "memory");
    else               asm volatile("s_waitcnt vmcnt(0)" ::: "memory");
    __builtin_amdgcn_s_barrier();            // raw: no forced vmcnt(0) drain
    __builtin_amdgcn_sched_barrier(0);       // pin LDS reads behind barrier
    if (f + 2 < ITEMS) stage(f + 2, nb);

    // shared K/V fragments (read once, used by both tiles)
    bf16x8 kfr[4][2], vfr[4][2];
#pragma unroll
    for (int cb = 0; cb < 4; ++cb)
#pragma unroll
      for (int hf = 0; hf < 2; ++hf) {
        kfr[cb][hf] = *(const bf16x8*)(&Ks[cur][(cb * 16 + l16) * 64 +
                                               ((hf * 4 + quad) ^ xa) * 8]);
        vfr[cb][hf] = *(const bf16x8*)(&Vs[cur][(cb * 16 + l16) * 64 +
                                               ((hf * 4 + quad) ^ xa) * 8]);
      }
    const int bAct = causal ? (f <= p) : 1;
    f32x4 scA[4], scB[4];
    qk_part(kfr, aqA, scA);
    if (bAct) qk_part(kfr, aqB, scB);       // B's MFMAs drain under A's softmax
    smpv_part(scA, vfr, oaccA, lsumA,
              causal && (f == ITEMS - 1), f * 64, qA + l16, quad, Cs);
    if (bAct)
      smpv_part(scB, vfr, oaccB, lsumB,
                causal && (f == p), f * 64, qB + l16, quad, Cs);
    cur = (cur == 2) ? 0 : cur + 1;
    nb = (nb == 2) ? 0 : nb + 1;
  }

  // epilogue per tile: reduce lsum over quads, write packed bf16 in place
  {
    float l = lsumA;
    l += __shfl_xor(l, 16, 64);
    l += __shfl_xor(l, 32, 64);
    float inv = 1.0f / l;
#pragma unroll
    for (int db = 0; db < 4; ++db) {
      u16x4 o;
#pragma unroll
      for (int rr = 0; rr < 4; ++rr) o[rr] = f2bf(oaccA[db][rr] * inv);
      *(u16x4*)(qh + (size_t)(qA + l16) * D_MODEL + db * 16 + quad * 4) = o;
    }
  }
  {
    float l = lsumB;
    l += __shfl_xor(l, 16, 64);
    l += __shfl_xor(l, 32, 64);
    float inv = 1.0f / l;
#pragma unroll
    for (int db = 0; db < 4; ++db) {
      u16x4 o;
#pragma unroll
      for (int rr = 0; rr < 4; ++rr) o[rr] = f2bf(oaccB[db][rr] * inv);
      *(u16x4*)(qh + (size_t)(qB + l16) * D_MODEL + db * 16 + quad * 4) = o;
    }
  }
}

// ---- final: d_out <- tmp, dtype per detected flag (SLOW PATH ONLY) ----
__global__ __launch_bounds__(256) void final_kernel(
    const float* __restrict__ tmp, void* __restrict__ out,
    const int* __restrict__ flag)
{
  const int bf = *flag;
  size_t i = ((size_t)blockIdx.x * 256 + threadIdx.x) * 8;
  f32x4 lo = *(const f32x4*)(tmp + i);
  f32x4 hi = *(const f32x4*)(tmp + i + 4);
  if (bf) {
    bf16x8 r;
    r[0] = (short)f2bf(lo[0]); r[1] = (short)f2bf(lo[1]);
    r[2] = (short)f2bf(lo[2]); r[3] = (short)f2bf(lo[3]);
    r[4] = (short)f2bf(hi[0]); r[5] = (short)f2bf(hi[1]);
    r[6] = (short)f2bf(hi[2]); r[7] = (short)f2bf(hi[3]);
    *(bf16x8*)((unsigned short*)out + i) = r;
  } else {
    *(f32x4*)((float*)out + i) = lo;
    *(f32x4*)((float*)out + i + 4) = hi;
  }
}

extern "C" void kernel_launch(void* const* d_in, const int* in_sizes, int n_in,
                              void* d_out, int out_size, void* d_ws, size_t ws_size,
                              hipStream_t stream) {
  const void* X  = d_in[0];
  const void* Wq = d_in[1];
  const void* Wk = d_in[2];
  const void* Wv = d_in[3];
  const void* Wo = d_in[4];
  const int* causal = (const int*)d_in[5];

  const size_t NE = (size_t)2 * SEQ * D_MODEL;   // 4,194,304 elems
  const size_t WE = (size_t)D_MODEL * D_MODEL;   // 1,048,576 elems
  int* flag0 = (int*)d_ws;

  // fast path layout (all in ws; d_out untouched until oproj writes it):
  //   [64B flag][kws 8M][vws 8M][Wb 8M][qd 8M][Xb 8M]  = 40 MB + 64
  unsigned short* kws = (unsigned short*)((char*)d_ws + 64);
  unsigned short* vws = kws + NE;
  unsigned short* Wb  = vws + NE;
  unsigned short* qdf = Wb + 4 * WE;             // fast-path Q/attn buffer
  unsigned short* Xbf = qdf + NE;                // fast-path X bf16

  const bool big = ws_size >= (size_t)64 + 40ull * 1024 * 1024;

  if (big) {
    // fast path: 4 kernels, dtype detected inline where needed
    hipLaunchKernelGGL(convert_kernel, dim3(2048, 5), dim3(256), 0, stream,
                       X, Wq, Wk, Wv, Wo, Xbf, Wb);
    hipLaunchKernelGGL(qkv_fast_kernel, dim3(768), dim3(256), 0, stream,
                       Xbf, Wb, qdf, kws, vws);
    hipLaunchKernelGGL(attn_kernel, dim3(512), dim3(256), 0, stream,
                       qdf, kws, vws, causal);
    hipLaunchKernelGGL(oproj_fast_kernel, dim3(256), dim3(256), 0, stream,
                       qdf, Wb + 3 * WE, (const unsigned short*)X, d_out);
  } else {
    // slow path: legacy layout (qd aliases d_out; tmp over dead K/V)
    float* tmp = (float*)kws;
    unsigned short* qd = (unsigned short*)d_out;
    hipLaunchKernelGGL(detect_kernel, dim3(1), dim3(64), 0, stream,
                       (const unsigned short*)X, flag0);
    hipLaunchKernelGGL(qkv_kernel, dim3(8, 32, 3), dim3(256), 0, stream,
                       X, Wq, Wk, Wv, flag0, qd, kws, vws);
    hipLaunchKernelGGL(attn_kernel, dim3(512), dim3(256), 0, stream,
                       qd, kws, vws, causal);
    hipLaunchKernelGGL(oproj_kernel, dim3(8, 32), dim3(256), 0, stream,
                       qd, Wo, flag0, tmp);
    hipLaunchKernelGGL(final_kernel, dim3(2048), dim3(256), 0, stream,
                       tmp, d_out, flag0);
  }
}